// Round 1
// baseline (279.865 us; speedup 1.0000x reference)
//
#include <hip/hip_runtime.h>

// ---------------------------------------------------------------------------
// SelfAttention with QA-LoRA quantized projections, MI355X (gfx950)
// Round 1: correctness-first bf16-MFMA baseline (m97-style GEMM + flash attn)
// ---------------------------------------------------------------------------

typedef __bf16 bf16x8 __attribute__((ext_vector_type(8)));
typedef float f32x4 __attribute__((ext_vector_type(4)));

#define MFMA(a, b, c) __builtin_amdgcn_mfma_f32_16x16x32_bf16(a, b, c, 0, 0, 0)

__device__ __forceinline__ void gld16(const void* g, void* l) {
  __builtin_amdgcn_global_load_lds(
      (const __attribute__((address_space(1))) void*)g,
      (__attribute__((address_space(3))) void*)l, 16, 0, 0);
}

// fake_quantize: returns the clipped, round-half-even INTEGER (not dequantized).
// Division by 0.1f (not *10) to match jnp's x / SCALE bit pattern.
__device__ __forceinline__ float fq(float v) {
  float q = rintf(v / 0.1f);           // v_rndne_f32: round half to even
  return fminf(fmaxf(q, -128.f), 127.f);
}

__device__ __forceinline__ float redmax16(float v) {
  v = fmaxf(v, __shfl_xor(v, 1));
  v = fmaxf(v, __shfl_xor(v, 2));
  v = fmaxf(v, __shfl_xor(v, 4));
  v = fmaxf(v, __shfl_xor(v, 8));
  return v;
}
__device__ __forceinline__ float redsum16(float v) {
  v += __shfl_xor(v, 1);
  v += __shfl_xor(v, 2);
  v += __shfl_xor(v, 4);
  v += __shfl_xor(v, 8);
  return v;
}

// ---------------- prep kernels ----------------

// 4 weight matrices (1024x1024 fp32) -> bf16 integer codes (exact for |q|<=128)
__global__ __launch_bounds__(256) void k_quant_w(
    const float* __restrict__ w0, const float* __restrict__ w1,
    const float* __restrict__ w2, const float* __restrict__ w3,
    __bf16* __restrict__ wq) {
  int i = blockIdx.x * 256 + threadIdx.x;          // 1M threads, 4 elems each
  int layer = i >> 18;
  const float* src = (layer == 0) ? w0 : (layer == 1) ? w1 : (layer == 2) ? w2 : w3;
  float4 v = ((const float4*)src)[i & 262143];
  __bf16 r[4] = {(__bf16)fq(v.x), (__bf16)fq(v.y), (__bf16)fq(v.z), (__bf16)fq(v.w)};
  *(uint2*)(wq + ((size_t)i << 2)) = *(uint2*)r;
}

// x fp32 -> bf16
__global__ __launch_bounds__(256) void k_xbf(const float* __restrict__ x,
                                             __bf16* __restrict__ xbf) {
  int i = blockIdx.x * 256 + threadIdx.x;          // 1M threads, 4 elems each
  float4 v = ((const float4*)x)[i];
  __bf16 r[4] = {(__bf16)v.x, (__bf16)v.y, (__bf16)v.z, (__bf16)v.w};
  *(uint2*)(xbf + ((size_t)i << 2)) = *(uint2*)r;
}

// x_avg[row][g] = mean of 64 consecutive fp32 features
__global__ __launch_bounds__(256) void k_xavg(const float* __restrict__ x,
                                              float* __restrict__ xavg) {
  int i = blockIdx.x * 256 + threadIdx.x;          // 65536 = 4096 rows * 16 groups
  int row = i >> 4, g = i & 15;
  const float4* p = (const float4*)(x + (size_t)row * 1024 + g * 64);
  float s = 0.f;
#pragma unroll
  for (int k = 0; k < 16; ++k) { float4 v = p[k]; s += v.x + v.y + v.z + v.w; }
  xavg[i] = s * (1.f / 64.f);
}

// delta[layer][o][g] = sum_r fq(dB[o][r])*0.1 * fq(dW[r][g])*0.1
__global__ __launch_bounds__(256) void k_delta(
    const float* __restrict__ dW0, const float* __restrict__ dB0,
    const float* __restrict__ dW1, const float* __restrict__ dB1,
    const float* __restrict__ dW2, const float* __restrict__ dB2,
    const float* __restrict__ dW3, const float* __restrict__ dB3,
    float* __restrict__ delta) {
  int i = blockIdx.x * 256 + threadIdx.x;          // 65536 = 4*1024*16
  int layer = i >> 14, o = (i >> 4) & 1023, g = i & 15;
  const float* dW = (layer == 0) ? dW0 : (layer == 1) ? dW1 : (layer == 2) ? dW2 : dW3;
  const float* dB = (layer == 0) ? dB0 : (layer == 1) ? dB1 : (layer == 2) ? dB2 : dB3;
  float acc = 0.f;
#pragma unroll
  for (int r = 0; r < 32; ++r)
    acc += (0.1f * fq(dB[o * 32 + r])) * (0.1f * fq(dW[r * 16 + g]));
  delta[i] = acc;
}

// ---------------- GEMM: y = 0.1*(A_bf16 @ Wq_int^T + x_avg @ (20*delta)^T) ----------------
// 128x128 tile, BK=64, 4 waves (2x2), 16x16x32 MFMA, global_load_lds 16B staging.
// mode 0: z selects Q/K/V output (bf16, scattered layouts). mode 1: fp32 to d_out.
__global__ __launch_bounds__(256) void k_gemm(
    const __bf16* __restrict__ A,       // [4096][1024]
    const __bf16* __restrict__ Wq,      // [4][1024][1024] int codes
    const float* __restrict__ deltas,   // [4][1024][16]
    const float* __restrict__ xavg,     // [4096][16]
    __bf16* __restrict__ qout,          // [bh][n][64]  (scaled by 1/8)
    __bf16* __restrict__ kout,          // [bh][n][64]
    __bf16* __restrict__ vout,          // [bh][64][n]  (pre-transposed for PV)
    float* __restrict__ fout,           // [4096][1024]
    int mode, int layer_base) {
  __shared__ __align__(16) __bf16 lA[128 * 64];
  __shared__ __align__(16) __bf16 lB[128 * 64];

  const int t = threadIdx.x;
  const int lane = t & 63;
  const int wv = t >> 6;
  const int bm = blockIdx.y;           // rows/128 (32)
  const int bn = blockIdx.x;           // cols/128 (8)
  const int layer = layer_base + blockIdx.z;
  const __bf16* Wl = Wq + ((size_t)layer << 20);
  const float* dl = deltas + (layer << 14);
  const int wm = wv >> 1, wn = wv & 1;
  const int fr = lane & 15, fq4 = lane >> 4;

  f32x4 acc[4][4];
#pragma unroll
  for (int mi = 0; mi < 4; ++mi)
#pragma unroll
    for (int ni = 0; ni < 4; ++ni) { f32x4 z = {0.f, 0.f, 0.f, 0.f}; acc[mi][ni] = z; }

  for (int kt = 0; kt < 16; ++kt) {
#pragma unroll
    for (int i = 0; i < 4; ++i) {
      int ci = i * 256 + t;
      int row = ci >> 3, c8 = ci & 7;
      gld16(A + (size_t)(bm * 128 + row) * 1024 + kt * 64 + c8 * 8,
            (char*)lA + (i * 256 + wv * 64) * 16);
      gld16(Wl + (size_t)(bn * 128 + row) * 1024 + kt * 64 + c8 * 8,
            (char*)lB + (i * 256 + wv * 64) * 16);
    }
    __syncthreads();
#pragma unroll
    for (int kk = 0; kk < 2; ++kk) {
      bf16x8 af[4], bfr[4];
#pragma unroll
      for (int mi = 0; mi < 4; ++mi)
        af[mi] = *(const bf16x8*)&lA[(wm * 64 + mi * 16 + fr) * 64 + kk * 32 + fq4 * 8];
#pragma unroll
      for (int ni = 0; ni < 4; ++ni)
        bfr[ni] = *(const bf16x8*)&lB[(wn * 64 + ni * 16 + fr) * 64 + kk * 32 + fq4 * 8];
#pragma unroll
      for (int mi = 0; mi < 4; ++mi)
#pragma unroll
        for (int ni = 0; ni < 4; ++ni)
          acc[mi][ni] = MFMA(af[mi], bfr[ni], acc[mi][ni]);
    }
    __syncthreads();
  }

  // LoRA as one extra MFMA K-step: A'=bf16(x_avg) (K=16, zero-padded to 32),
  // B'=bf16(20*delta) so y_total = 0.1*(base + x_avg@(20*delta)^T).
  {
    int row = t >> 1, half = t & 1;
#pragma unroll
    for (int g = 0; g < 16; ++g) {
      lA[row * 64 + half * 16 + g] =
          half ? (__bf16)0.f : (__bf16)xavg[(bm * 128 + row) * 16 + g];
      lB[row * 64 + half * 16 + g] =
          half ? (__bf16)0.f : (__bf16)(20.f * dl[(bn * 128 + row) * 16 + g]);
    }
    __syncthreads();
    bf16x8 af[4], bfr[4];
#pragma unroll
    for (int mi = 0; mi < 4; ++mi)
      af[mi] = *(const bf16x8*)&lA[(wm * 64 + mi * 16 + fr) * 64 + fq4 * 8];
#pragma unroll
    for (int ni = 0; ni < 4; ++ni)
      bfr[ni] = *(const bf16x8*)&lB[(wn * 64 + ni * 16 + fr) * 64 + fq4 * 8];
#pragma unroll
    for (int mi = 0; mi < 4; ++mi)
#pragma unroll
      for (int ni = 0; ni < 4; ++ni)
        acc[mi][ni] = MFMA(af[mi], bfr[ni], acc[mi][ni]);
  }

  const float outmul = (mode == 0 && blockIdx.z == 0) ? 0.0125f : 0.1f;  // q: fold 1/sqrt(64)
#pragma unroll
  for (int mi = 0; mi < 4; ++mi)
#pragma unroll
    for (int ni = 0; ni < 4; ++ni) {
      int o = bn * 128 + wn * 64 + ni * 16 + fr;
#pragma unroll
      for (int j = 0; j < 4; ++j) {
        int m = bm * 128 + wm * 64 + mi * 16 + fq4 * 4 + j;
        float v = acc[mi][ni][j] * outmul;
        if (mode == 0) {
          int b = m >> 11, nr = m & 2047;
          int h = o >> 6, d = o & 63;
          if (blockIdx.z == 0)
            qout[((size_t)(b * 16 + h) * 2048 + nr) * 64 + d] = (__bf16)v;
          else if (blockIdx.z == 1)
            kout[((size_t)(b * 16 + h) * 2048 + nr) * 64 + d] = (__bf16)v;
          else
            vout[((size_t)(b * 16 + h) * 64 + d) * 2048 + nr] = (__bf16)v;
        } else {
          fout[(size_t)m * 1024 + o] = v;
        }
      }
    }
}

// ---------------- flash attention ----------------
// One block = one (b,h) x 64 q-rows; 4 waves x 16 rows. K-tiles of 64 keys.
__global__ __launch_bounds__(256) void k_attn(
    const __bf16* __restrict__ qb,   // [bh][n][64] (pre-scaled by 1/8)
    const __bf16* __restrict__ kb,   // [bh][n][64]
    const __bf16* __restrict__ vbt,  // [bh][64][n]
    __bf16* __restrict__ attnb,      // [4096][1024]
    float* __restrict__ aavg) {      // [4096][16]
  __shared__ __align__(16) __bf16 lK[64 * 64];
  __shared__ __align__(16) __bf16 lVT[64 * 64];
  __shared__ __align__(16) __bf16 lP[4 * 16 * 64];

  const int t = threadIdx.x, lane = t & 63, wv = t >> 6;
  const int bh = blockIdx.y;           // 0..31
  const int qt = blockIdx.x;           // 0..31
  const int fr = lane & 15, fq4 = lane >> 4;
  const int qrow0 = qt * 64 + wv * 16;
  const size_t hbase = (size_t)bh * 2048 * 64;
  __bf16* lPw = lP + wv * 16 * 64;

  bf16x8 qf[2];
#pragma unroll
  for (int kk = 0; kk < 2; ++kk)
    qf[kk] = *(const bf16x8*)(qb + hbase + (size_t)(qrow0 + fr) * 64 + kk * 32 + fq4 * 8);

  f32x4 o[4];
#pragma unroll
  for (int di = 0; di < 4; ++di) { f32x4 z = {0.f, 0.f, 0.f, 0.f}; o[di] = z; }
  float mrun[4], lrun[4];
#pragma unroll
  for (int j = 0; j < 4; ++j) { mrun[j] = -__builtin_inff(); lrun[j] = 0.f; }

  for (int kt = 0; kt < 32; ++kt) {
    // stage K tile [key][d] and V^T tile [d][key] (both linear, gld16)
#pragma unroll
    for (int i = 0; i < 2; ++i) {
      int ci = i * 256 + t;
      int r = ci >> 3, c8 = ci & 7;
      gld16(kb + hbase + (size_t)(kt * 64 + r) * 64 + c8 * 8,
            (char*)lK + (i * 256 + wv * 64) * 16);
      gld16(vbt + hbase + (size_t)r * 2048 + kt * 64 + c8 * 8,
            (char*)lVT + (i * 256 + wv * 64) * 16);
    }
    __syncthreads();

    // S = Q K^T (q pre-scaled by 1/8)
    f32x4 s[4];
#pragma unroll
    for (int ni = 0; ni < 4; ++ni) { f32x4 z = {0.f, 0.f, 0.f, 0.f}; s[ni] = z; }
#pragma unroll
    for (int kk = 0; kk < 2; ++kk)
#pragma unroll
      for (int ni = 0; ni < 4; ++ni) {
        bf16x8 kf = *(const bf16x8*)&lK[(ni * 16 + fr) * 64 + kk * 32 + fq4 * 8];
        s[ni] = MFMA(qf[kk], kf, s[ni]);
      }

    // online softmax (rows j, 16 lanes per row-group)
#pragma unroll
    for (int j = 0; j < 4; ++j) {
      float rm = fmaxf(fmaxf(s[0][j], s[1][j]), fmaxf(s[2][j], s[3][j]));
      rm = redmax16(rm);
      float mnew = fmaxf(mrun[j], rm);
      float alpha = __expf(mrun[j] - mnew);
      mrun[j] = mnew;
      float rs = 0.f;
#pragma unroll
      for (int ni = 0; ni < 4; ++ni) {
        float p = __expf(s[ni][j] - mnew);
        rs += p;
        lPw[(fq4 * 4 + j) * 64 + ni * 16 + fr] = (__bf16)p;
      }
      lrun[j] = lrun[j] * alpha + redsum16(rs);
#pragma unroll
      for (int di = 0; di < 4; ++di) o[di][j] *= alpha;
    }
    __syncthreads();   // order P writes (per-lane scatter) before cross-lane reads

    // O += P V
#pragma unroll
    for (int kk = 0; kk < 2; ++kk) {
      bf16x8 pa = *(const bf16x8*)&lPw[fr * 64 + kk * 32 + fq4 * 8];
#pragma unroll
      for (int di = 0; di < 4; ++di) {
        bf16x8 vf = *(const bf16x8*)&lVT[(di * 16 + fr) * 64 + kk * 32 + fq4 * 8];
        o[di] = MFMA(pa, vf, o[di]);
      }
    }
    __syncthreads();   // before next tile's staging overwrites lK/lVT
  }

  // epilogue: normalize, write attn bf16 [m][h*64+d] + per-row head mean (fp32)
  const int b = bh >> 4, h = bh & 15;
#pragma unroll
  for (int j = 0; j < 4; ++j) {
    float inv = 1.f / lrun[j];
    int nr = qt * 64 + wv * 16 + fq4 * 4 + j;
    size_t mrow = ((size_t)(b * 2048 + nr)) * 1024 + h * 64;
    float rowsum = 0.f;
#pragma unroll
    for (int di = 0; di < 4; ++di) {
      float vv = o[di][j] * inv;
      attnb[mrow + di * 16 + fr] = (__bf16)vv;
      rowsum += vv;
    }
    rowsum = redsum16(rowsum);
    if (fr == 0) aavg[(size_t)(b * 2048 + nr) * 16 + h] = rowsum * (1.f / 64.f);
  }
}

// ---------------- launch ----------------
extern "C" void kernel_launch(void* const* d_in, const int* in_sizes, int n_in,
                              void* d_out, int out_size, void* d_ws, size_t ws_size,
                              hipStream_t stream) {
  const float* x = (const float*)d_in[0];
  const float* w_[4]  = {(const float*)d_in[1], (const float*)d_in[4],
                         (const float*)d_in[7], (const float*)d_in[10]};
  const float* dW_[4] = {(const float*)d_in[2], (const float*)d_in[5],
                         (const float*)d_in[8], (const float*)d_in[11]};
  const float* dB_[4] = {(const float*)d_in[3], (const float*)d_in[6],
                         (const float*)d_in[9], (const float*)d_in[12]};
  float* out = (float*)d_out;

  char* ws = (char*)d_ws;
  const size_t MB = 1ull << 20;
  __bf16* xbf   = (__bf16*)(ws);                 // 8 MB
  __bf16* wq    = (__bf16*)(ws + 8 * MB);        // 8 MB (4 layers)
  __bf16* qb    = (__bf16*)(ws + 16 * MB);       // 8 MB
  __bf16* kb    = (__bf16*)(ws + 24 * MB);       // 8 MB
  __bf16* vbt   = (__bf16*)(ws + 32 * MB);       // 8 MB
  __bf16* attnb = (__bf16*)(ws + 40 * MB);       // 8 MB
  float* xavg   = (float*)(ws + 48 * MB);                  // 256 KB
  float* aavg   = (float*)(ws + 48 * MB + 256 * 1024);     // 256 KB
  float* delta  = (float*)(ws + 48 * MB + 512 * 1024);     // 256 KB

  k_quant_w<<<4096, 256, 0, stream>>>(w_[0], w_[1], w_[2], w_[3], wq);
  k_xbf<<<4096, 256, 0, stream>>>(x, xbf);
  k_xavg<<<256, 256, 0, stream>>>(x, xavg);
  k_delta<<<256, 256, 0, stream>>>(dW_[0], dB_[0], dW_[1], dB_[1],
                                   dW_[2], dB_[2], dW_[3], dB_[3], delta);
  k_gemm<<<dim3(8, 32, 3), 256, 0, stream>>>(xbf, wq, delta, xavg,
                                             qb, kb, vbt, nullptr, 0, 0);
  k_attn<<<dim3(32, 32), 256, 0, stream>>>(qb, kb, vbt, attnb, aavg);
  k_gemm<<<dim3(8, 32, 1), 256, 0, stream>>>(attnb, wq, delta, aavg,
                                             nullptr, nullptr, nullptr, out, 1, 3);
}

// Round 2
// 250.252 us; speedup vs baseline: 1.1183x; 1.1183x over previous
//
#include <hip/hip_runtime.h>

// ---------------------------------------------------------------------------
// SelfAttention with QA-LoRA quantized projections, MI355X (gfx950)
// Round 2: attn LDS XOR-swizzle (T2) + single-barrier double-buffered K/V +
//          setprio around MFMA. GEMM/prep unchanged from round 1.
// ---------------------------------------------------------------------------

typedef __bf16 bf16x8 __attribute__((ext_vector_type(8)));
typedef float f32x4 __attribute__((ext_vector_type(4)));

#define MFMA(a, b, c) __builtin_amdgcn_mfma_f32_16x16x32_bf16(a, b, c, 0, 0, 0)

__device__ __forceinline__ void gld16(const void* g, void* l) {
  __builtin_amdgcn_global_load_lds(
      (const __attribute__((address_space(1))) void*)g,
      (__attribute__((address_space(3))) void*)l, 16, 0, 0);
}

// fake_quantize: returns the clipped, round-half-even INTEGER (not dequantized).
__device__ __forceinline__ float fq(float v) {
  float q = rintf(v / 0.1f);           // v_rndne_f32: round half to even
  return fminf(fmaxf(q, -128.f), 127.f);
}

__device__ __forceinline__ float redmax16(float v) {
  v = fmaxf(v, __shfl_xor(v, 1));
  v = fmaxf(v, __shfl_xor(v, 2));
  v = fmaxf(v, __shfl_xor(v, 4));
  v = fmaxf(v, __shfl_xor(v, 8));
  return v;
}
__device__ __forceinline__ float redsum16(float v) {
  v += __shfl_xor(v, 1);
  v += __shfl_xor(v, 2);
  v += __shfl_xor(v, 4);
  v += __shfl_xor(v, 8);
  return v;
}

// ---------------- prep kernels ----------------

__global__ __launch_bounds__(256) void k_quant_w(
    const float* __restrict__ w0, const float* __restrict__ w1,
    const float* __restrict__ w2, const float* __restrict__ w3,
    __bf16* __restrict__ wq) {
  int i = blockIdx.x * 256 + threadIdx.x;
  int layer = i >> 18;
  const float* src = (layer == 0) ? w0 : (layer == 1) ? w1 : (layer == 2) ? w2 : w3;
  float4 v = ((const float4*)src)[i & 262143];
  __bf16 r[4] = {(__bf16)fq(v.x), (__bf16)fq(v.y), (__bf16)fq(v.z), (__bf16)fq(v.w)};
  *(uint2*)(wq + ((size_t)i << 2)) = *(uint2*)r;
}

__global__ __launch_bounds__(256) void k_xbf(const float* __restrict__ x,
                                             __bf16* __restrict__ xbf) {
  int i = blockIdx.x * 256 + threadIdx.x;
  float4 v = ((const float4*)x)[i];
  __bf16 r[4] = {(__bf16)v.x, (__bf16)v.y, (__bf16)v.z, (__bf16)v.w};
  *(uint2*)(xbf + ((size_t)i << 2)) = *(uint2*)r;
}

__global__ __launch_bounds__(256) void k_xavg(const float* __restrict__ x,
                                              float* __restrict__ xavg) {
  int i = blockIdx.x * 256 + threadIdx.x;
  int row = i >> 4, g = i & 15;
  const float4* p = (const float4*)(x + (size_t)row * 1024 + g * 64);
  float s = 0.f;
#pragma unroll
  for (int k = 0; k < 16; ++k) { float4 v = p[k]; s += v.x + v.y + v.z + v.w; }
  xavg[i] = s * (1.f / 64.f);
}

__global__ __launch_bounds__(256) void k_delta(
    const float* __restrict__ dW0, const float* __restrict__ dB0,
    const float* __restrict__ dW1, const float* __restrict__ dB1,
    const float* __restrict__ dW2, const float* __restrict__ dB2,
    const float* __restrict__ dW3, const float* __restrict__ dB3,
    float* __restrict__ delta) {
  int i = blockIdx.x * 256 + threadIdx.x;
  int layer = i >> 14, o = (i >> 4) & 1023, g = i & 15;
  const float* dW = (layer == 0) ? dW0 : (layer == 1) ? dW1 : (layer == 2) ? dW2 : dW3;
  const float* dB = (layer == 0) ? dB0 : (layer == 1) ? dB1 : (layer == 2) ? dB2 : dB3;
  float acc = 0.f;
#pragma unroll
  for (int r = 0; r < 32; ++r)
    acc += (0.1f * fq(dB[o * 32 + r])) * (0.1f * fq(dW[r * 16 + g]));
  delta[i] = acc;
}

// ---------------- GEMM (unchanged from round 1) ----------------
__global__ __launch_bounds__(256) void k_gemm(
    const __bf16* __restrict__ A,       // [4096][1024]
    const __bf16* __restrict__ Wq,      // [4][1024][1024] int codes
    const float* __restrict__ deltas,   // [4][1024][16]
    const float* __restrict__ xavg,     // [4096][16]
    __bf16* __restrict__ qout,          // [bh][n][64]  (scaled by 1/8)
    __bf16* __restrict__ kout,          // [bh][n][64]
    __bf16* __restrict__ vout,          // [bh][64][n]
    float* __restrict__ fout,           // [4096][1024]
    int mode, int layer_base) {
  __shared__ __align__(16) __bf16 lA[128 * 64];
  __shared__ __align__(16) __bf16 lB[128 * 64];

  const int t = threadIdx.x;
  const int lane = t & 63;
  const int wv = t >> 6;
  const int bm = blockIdx.y;
  const int bn = blockIdx.x;
  const int layer = layer_base + blockIdx.z;
  const __bf16* Wl = Wq + ((size_t)layer << 20);
  const float* dl = deltas + (layer << 14);
  const int wm = wv >> 1, wn = wv & 1;
  const int fr = lane & 15, fq4 = lane >> 4;

  f32x4 acc[4][4];
#pragma unroll
  for (int mi = 0; mi < 4; ++mi)
#pragma unroll
    for (int ni = 0; ni < 4; ++ni) { f32x4 z = {0.f, 0.f, 0.f, 0.f}; acc[mi][ni] = z; }

  for (int kt = 0; kt < 16; ++kt) {
#pragma unroll
    for (int i = 0; i < 4; ++i) {
      int ci = i * 256 + t;
      int row = ci >> 3, c8 = ci & 7;
      gld16(A + (size_t)(bm * 128 + row) * 1024 + kt * 64 + c8 * 8,
            (char*)lA + (i * 256 + wv * 64) * 16);
      gld16(Wl + (size_t)(bn * 128 + row) * 1024 + kt * 64 + c8 * 8,
            (char*)lB + (i * 256 + wv * 64) * 16);
    }
    __syncthreads();
#pragma unroll
    for (int kk = 0; kk < 2; ++kk) {
      bf16x8 af[4], bfr[4];
#pragma unroll
      for (int mi = 0; mi < 4; ++mi)
        af[mi] = *(const bf16x8*)&lA[(wm * 64 + mi * 16 + fr) * 64 + kk * 32 + fq4 * 8];
#pragma unroll
      for (int ni = 0; ni < 4; ++ni)
        bfr[ni] = *(const bf16x8*)&lB[(wn * 64 + ni * 16 + fr) * 64 + kk * 32 + fq4 * 8];
#pragma unroll
      for (int mi = 0; mi < 4; ++mi)
#pragma unroll
        for (int ni = 0; ni < 4; ++ni)
          acc[mi][ni] = MFMA(af[mi], bfr[ni], acc[mi][ni]);
    }
    __syncthreads();
  }

  // LoRA as one extra MFMA K-step
  {
    int row = t >> 1, half = t & 1;
#pragma unroll
    for (int g = 0; g < 16; ++g) {
      lA[row * 64 + half * 16 + g] =
          half ? (__bf16)0.f : (__bf16)xavg[(bm * 128 + row) * 16 + g];
      lB[row * 64 + half * 16 + g] =
          half ? (__bf16)0.f : (__bf16)(20.f * dl[(bn * 128 + row) * 16 + g]);
    }
    __syncthreads();
    bf16x8 af[4], bfr[4];
#pragma unroll
    for (int mi = 0; mi < 4; ++mi)
      af[mi] = *(const bf16x8*)&lA[(wm * 64 + mi * 16 + fr) * 64 + fq4 * 8];
#pragma unroll
    for (int ni = 0; ni < 4; ++ni)
      bfr[ni] = *(const bf16x8*)&lB[(wn * 64 + ni * 16 + fr) * 64 + fq4 * 8];
#pragma unroll
    for (int mi = 0; mi < 4; ++mi)
#pragma unroll
      for (int ni = 0; ni < 4; ++ni)
        acc[mi][ni] = MFMA(af[mi], bfr[ni], acc[mi][ni]);
  }

  const float outmul = (mode == 0 && blockIdx.z == 0) ? 0.0125f : 0.1f;
#pragma unroll
  for (int mi = 0; mi < 4; ++mi)
#pragma unroll
    for (int ni = 0; ni < 4; ++ni) {
      int o = bn * 128 + wn * 64 + ni * 16 + fr;
#pragma unroll
      for (int j = 0; j < 4; ++j) {
        int m = bm * 128 + wm * 64 + mi * 16 + fq4 * 4 + j;
        float v = acc[mi][ni][j] * outmul;
        if (mode == 0) {
          int b = m >> 11, nr = m & 2047;
          int h = o >> 6, d = o & 63;
          if (blockIdx.z == 0)
            qout[((size_t)(b * 16 + h) * 2048 + nr) * 64 + d] = (__bf16)v;
          else if (blockIdx.z == 1)
            kout[((size_t)(b * 16 + h) * 2048 + nr) * 64 + d] = (__bf16)v;
          else
            vout[((size_t)(b * 16 + h) * 64 + d) * 2048 + nr] = (__bf16)v;
        } else {
          fout[(size_t)m * 1024 + o] = v;
        }
      }
    }
}

// ---------------- flash attention (round 2) ----------------
// XOR chunk-swizzle (16B granularity, chunk ^= row&7) on lK/lVT (via
// pre-swizzled global source for global_load_lds) and lP (direct).
// Double-buffered K/V -> ONE barrier per K-tile. lP is wave-private
// (same-wave DS ops are in-order) -> no barrier needed for it.
__global__ __launch_bounds__(256) void k_attn(
    const __bf16* __restrict__ qb,   // [bh][n][64] (pre-scaled by 1/8)
    const __bf16* __restrict__ kb,   // [bh][n][64]
    const __bf16* __restrict__ vbt,  // [bh][64][n]
    __bf16* __restrict__ attnb,      // [4096][1024]
    float* __restrict__ aavg) {      // [4096][16]
  __shared__ __align__(16) __bf16 lK[2][64 * 64];
  __shared__ __align__(16) __bf16 lVT[2][64 * 64];
  __shared__ __align__(16) __bf16 lP[4 * 16 * 64];

  const int t = threadIdx.x, lane = t & 63, wv = t >> 6;
  const int bh = blockIdx.y;
  const int qt = blockIdx.x;
  const int fr = lane & 15, fq4 = lane >> 4;
  const int qrow0 = qt * 64 + wv * 16;
  const size_t hbase = (size_t)bh * 2048 * 64;
  __bf16* lPw = lP + wv * 16 * 64;

  // staging coordinates for this thread (slot = 16B chunk), source pre-swizzled
  const int srow0 = t >> 3, sc0 = (t & 7) ^ (srow0 & 7);
  const int srow1 = (256 + t) >> 3, sc1 = (t & 7) ^ (srow1 & 7);
  const int dst0 = (wv * 64) * 16, dst1 = (256 + wv * 64) * 16;

  bf16x8 qf[2];
#pragma unroll
  for (int kk = 0; kk < 2; ++kk)
    qf[kk] = *(const bf16x8*)(qb + hbase + (size_t)(qrow0 + fr) * 64 + kk * 32 + fq4 * 8);

  f32x4 o[4];
#pragma unroll
  for (int di = 0; di < 4; ++di) { f32x4 z = {0.f, 0.f, 0.f, 0.f}; o[di] = z; }
  float mrun[4], lrun[4];
#pragma unroll
  for (int j = 0; j < 4; ++j) { mrun[j] = -__builtin_inff(); lrun[j] = 0.f; }

  // prologue: stage tile 0 into buf 0
  gld16(kb + hbase + (size_t)(srow0)*64 + sc0 * 8, (char*)lK[0] + dst0);
  gld16(vbt + hbase + (size_t)srow0 * 2048 + sc0 * 8, (char*)lVT[0] + dst0);
  gld16(kb + hbase + (size_t)(srow1)*64 + sc1 * 8, (char*)lK[0] + dst1);
  gld16(vbt + hbase + (size_t)srow1 * 2048 + sc1 * 8, (char*)lVT[0] + dst1);
  __syncthreads();

  int cur = 0;
  for (int kt = 0; kt < 32; ++kt) {
    // issue next tile's staging into buf^1 (completes by end-of-loop barrier)
    if (kt + 1 < 32) {
      int kn = (kt + 1) * 64;
      gld16(kb + hbase + (size_t)(kn + srow0) * 64 + sc0 * 8, (char*)lK[cur ^ 1] + dst0);
      gld16(vbt + hbase + (size_t)srow0 * 2048 + kn + sc0 * 8, (char*)lVT[cur ^ 1] + dst0);
      gld16(kb + hbase + (size_t)(kn + srow1) * 64 + sc1 * 8, (char*)lK[cur ^ 1] + dst1);
      gld16(vbt + hbase + (size_t)srow1 * 2048 + kn + sc1 * 8, (char*)lVT[cur ^ 1] + dst1);
    }

    // S = Q K^T (q pre-scaled by 1/8); swizzled reads
    f32x4 s[4];
#pragma unroll
    for (int ni = 0; ni < 4; ++ni) { f32x4 z = {0.f, 0.f, 0.f, 0.f}; s[ni] = z; }
    __builtin_amdgcn_s_setprio(1);
#pragma unroll
    for (int kk = 0; kk < 2; ++kk)
#pragma unroll
      for (int ni = 0; ni < 4; ++ni) {
        bf16x8 kf = *(const bf16x8*)&lK[cur][(ni * 16 + fr) * 64 +
                                            (((kk << 2) | fq4) ^ (fr & 7)) * 8];
        s[ni] = MFMA(qf[kk], kf, s[ni]);
      }
    __builtin_amdgcn_s_setprio(0);

    // online softmax; write P into wave-private swizzled lP
#pragma unroll
    for (int j = 0; j < 4; ++j) {
      float rm = fmaxf(fmaxf(s[0][j], s[1][j]), fmaxf(s[2][j], s[3][j]));
      rm = redmax16(rm);
      float mnew = fmaxf(mrun[j], rm);
      float alpha = __expf(mrun[j] - mnew);
      mrun[j] = mnew;
      int r = fq4 * 4 + j;
      float rs = 0.f;
#pragma unroll
      for (int ni = 0; ni < 4; ++ni) {
        float p = __expf(s[ni][j] - mnew);
        rs += p;
        int chunk = ni * 2 + (fr >> 3);
        lPw[r * 64 + ((chunk ^ (r & 7)) << 3) + (fr & 7)] = (__bf16)p;
      }
      lrun[j] = lrun[j] * alpha + redsum16(rs);
#pragma unroll
      for (int di = 0; di < 4; ++di) o[di][j] *= alpha;
    }

    // O += P V   (same-wave DS ordering makes lP writes visible; no barrier)
    __builtin_amdgcn_s_setprio(1);
#pragma unroll
    for (int kk = 0; kk < 2; ++kk) {
      bf16x8 pa = *(const bf16x8*)&lPw[fr * 64 + (((kk << 2) | fq4) ^ (fr & 7)) * 8];
#pragma unroll
      for (int di = 0; di < 4; ++di) {
        bf16x8 vf = *(const bf16x8*)&lVT[cur][(di * 16 + fr) * 64 +
                                              (((kk << 2) | fq4) ^ (fr & 7)) * 8];
        o[di] = MFMA(pa, vf, o[di]);
      }
    }
    __builtin_amdgcn_s_setprio(0);

    __syncthreads();   // staging of kt+1 complete; buf[cur] free for kt+2
    cur ^= 1;
  }

  // epilogue
  const int b = bh >> 4, h = bh & 15;
#pragma unroll
  for (int j = 0; j < 4; ++j) {
    float inv = 1.f / lrun[j];
    int nr = qt * 64 + wv * 16 + fq4 * 4 + j;
    size_t mrow = ((size_t)(b * 2048 + nr)) * 1024 + h * 64;
    float rowsum = 0.f;
#pragma unroll
    for (int di = 0; di < 4; ++di) {
      float vv = o[di][j] * inv;
      attnb[mrow + di * 16 + fr] = (__bf16)vv;
      rowsum += vv;
    }
    rowsum = redsum16(rowsum);
    if (fr == 0) aavg[(size_t)(b * 2048 + nr) * 16 + h] = rowsum * (1.f / 64.f);
  }
}

// ---------------- launch ----------------
extern "C" void kernel_launch(void* const* d_in, const int* in_sizes, int n_in,
                              void* d_out, int out_size, void* d_ws, size_t ws_size,
                              hipStream_t stream) {
  const float* x = (const float*)d_in[0];
  const float* w_[4]  = {(const float*)d_in[1], (const float*)d_in[4],
                         (const float*)d_in[7], (const float*)d_in[10]};
  const float* dW_[4] = {(const float*)d_in[2], (const float*)d_in[5],
                         (const float*)d_in[8], (const float*)d_in[11]};
  const float* dB_[4] = {(const float*)d_in[3], (const float*)d_in[6],
                         (const float*)d_in[9], (const float*)d_in[12]};
  float* out = (float*)d_out;

  char* ws = (char*)d_ws;
  const size_t MB = 1ull << 20;
  __bf16* xbf   = (__bf16*)(ws);                 // 8 MB
  __bf16* wq    = (__bf16*)(ws + 8 * MB);        // 8 MB (4 layers)
  __bf16* qb    = (__bf16*)(ws + 16 * MB);       // 8 MB
  __bf16* kb    = (__bf16*)(ws + 24 * MB);       // 8 MB
  __bf16* vbt   = (__bf16*)(ws + 32 * MB);       // 8 MB
  __bf16* attnb = (__bf16*)(ws + 40 * MB);       // 8 MB
  float* xavg   = (float*)(ws + 48 * MB);                  // 256 KB
  float* aavg   = (float*)(ws + 48 * MB + 256 * 1024);     // 256 KB
  float* delta  = (float*)(ws + 48 * MB + 512 * 1024);     // 256 KB

  k_quant_w<<<4096, 256, 0, stream>>>(w_[0], w_[1], w_[2], w_[3], wq);
  k_xbf<<<4096, 256, 0, stream>>>(x, xbf);
  k_xavg<<<256, 256, 0, stream>>>(x, xavg);
  k_delta<<<256, 256, 0, stream>>>(dW_[0], dB_[0], dW_[1], dB_[1],
                                   dW_[2], dB_[2], dW_[3], dB_[3], delta);
  k_gemm<<<dim3(8, 32, 3), 256, 0, stream>>>(xbf, wq, delta, xavg,
                                             qb, kb, vbt, nullptr, 0, 0);
  k_attn<<<dim3(32, 32), 256, 0, stream>>>(qb, kb, vbt, attnb, aavg);
  k_gemm<<<dim3(8, 32, 1), 256, 0, stream>>>(attnb, wq, delta, aavg,
                                             nullptr, nullptr, nullptr, out, 1, 3);
}

// Round 3
// 203.504 us; speedup vs baseline: 1.3752x; 1.2297x over previous
//
#include <hip/hip_runtime.h>

// ---------------------------------------------------------------------------
// SelfAttention with QA-LoRA quantized projections, MI355X (gfx950)
// Round 3: attn softmax VALU-cut — log2-domain exp, defer-max (m=0, T13),
//          ones-column MFMA for the softmax denominator (no shuffles in the
//          K-loop), + V^T epilogue 8B packed stores in the QKV GEMM.
// ---------------------------------------------------------------------------

typedef __bf16 bf16x8 __attribute__((ext_vector_type(8)));
typedef float f32x4 __attribute__((ext_vector_type(4)));

#define MFMA(a, b, c) __builtin_amdgcn_mfma_f32_16x16x32_bf16(a, b, c, 0, 0, 0)

__device__ __forceinline__ void gld16(const void* g, void* l) {
  __builtin_amdgcn_global_load_lds(
      (const __attribute__((address_space(1))) void*)g,
      (__attribute__((address_space(3))) void*)l, 16, 0, 0);
}

// fake_quantize: returns the clipped, round-half-even INTEGER (not dequantized).
__device__ __forceinline__ float fq(float v) {
  float q = rintf(v / 0.1f);           // v_rndne_f32: round half to even
  return fminf(fmaxf(q, -128.f), 127.f);
}

__device__ __forceinline__ float redmax16(float v) {
  v = fmaxf(v, __shfl_xor(v, 1));
  v = fmaxf(v, __shfl_xor(v, 2));
  v = fmaxf(v, __shfl_xor(v, 4));
  v = fmaxf(v, __shfl_xor(v, 8));
  return v;
}
__device__ __forceinline__ float redsum16(float v) {
  v += __shfl_xor(v, 1);
  v += __shfl_xor(v, 2);
  v += __shfl_xor(v, 4);
  v += __shfl_xor(v, 8);
  return v;
}

// ---------------- prep kernels ----------------

__global__ __launch_bounds__(256) void k_quant_w(
    const float* __restrict__ w0, const float* __restrict__ w1,
    const float* __restrict__ w2, const float* __restrict__ w3,
    __bf16* __restrict__ wq) {
  int i = blockIdx.x * 256 + threadIdx.x;
  int layer = i >> 18;
  const float* src = (layer == 0) ? w0 : (layer == 1) ? w1 : (layer == 2) ? w2 : w3;
  float4 v = ((const float4*)src)[i & 262143];
  __bf16 r[4] = {(__bf16)fq(v.x), (__bf16)fq(v.y), (__bf16)fq(v.z), (__bf16)fq(v.w)};
  *(uint2*)(wq + ((size_t)i << 2)) = *(uint2*)r;
}

__global__ __launch_bounds__(256) void k_xbf(const float* __restrict__ x,
                                             __bf16* __restrict__ xbf) {
  int i = blockIdx.x * 256 + threadIdx.x;
  float4 v = ((const float4*)x)[i];
  __bf16 r[4] = {(__bf16)v.x, (__bf16)v.y, (__bf16)v.z, (__bf16)v.w};
  *(uint2*)(xbf + ((size_t)i << 2)) = *(uint2*)r;
}

__global__ __launch_bounds__(256) void k_xavg(const float* __restrict__ x,
                                              float* __restrict__ xavg) {
  int i = blockIdx.x * 256 + threadIdx.x;
  int row = i >> 4, g = i & 15;
  const float4* p = (const float4*)(x + (size_t)row * 1024 + g * 64);
  float s = 0.f;
#pragma unroll
  for (int k = 0; k < 16; ++k) { float4 v = p[k]; s += v.x + v.y + v.z + v.w; }
  xavg[i] = s * (1.f / 64.f);
}

__global__ __launch_bounds__(256) void k_delta(
    const float* __restrict__ dW0, const float* __restrict__ dB0,
    const float* __restrict__ dW1, const float* __restrict__ dB1,
    const float* __restrict__ dW2, const float* __restrict__ dB2,
    const float* __restrict__ dW3, const float* __restrict__ dB3,
    float* __restrict__ delta) {
  int i = blockIdx.x * 256 + threadIdx.x;
  int layer = i >> 14, o = (i >> 4) & 1023, g = i & 15;
  const float* dW = (layer == 0) ? dW0 : (layer == 1) ? dW1 : (layer == 2) ? dW2 : dW3;
  const float* dB = (layer == 0) ? dB0 : (layer == 1) ? dB1 : (layer == 2) ? dB2 : dB3;
  float acc = 0.f;
#pragma unroll
  for (int r = 0; r < 32; ++r)
    acc += (0.1f * fq(dB[o * 32 + r])) * (0.1f * fq(dW[r * 16 + g]));
  delta[i] = acc;
}

// ---------------- GEMM ----------------
// 128x128 tile, BK=64, 4 waves (2x2), 16x16x32 MFMA, global_load_lds 16B.
// mode 0: z selects Q/K/V (bf16). Q is scaled by 0.1/8*log2e (log2-domain
// softmax downstream). V^T written with j-packed 8B stores.
// mode 1: fp32 to d_out.
__global__ __launch_bounds__(256) void k_gemm(
    const __bf16* __restrict__ A,       // [4096][1024]
    const __bf16* __restrict__ Wq,      // [4][1024][1024] int codes
    const float* __restrict__ deltas,   // [4][1024][16]
    const float* __restrict__ xavg,     // [4096][16]
    __bf16* __restrict__ qout,          // [bh][n][64]
    __bf16* __restrict__ kout,          // [bh][n][64]
    __bf16* __restrict__ vout,          // [bh][64][n]
    float* __restrict__ fout,           // [4096][1024]
    int mode, int layer_base) {
  __shared__ __align__(16) __bf16 lA[128 * 64];
  __shared__ __align__(16) __bf16 lB[128 * 64];

  const int t = threadIdx.x;
  const int lane = t & 63;
  const int wv = t >> 6;
  const int bm = blockIdx.y;
  const int bn = blockIdx.x;
  const int layer = layer_base + blockIdx.z;
  const __bf16* Wl = Wq + ((size_t)layer << 20);
  const float* dl = deltas + (layer << 14);
  const int wm = wv >> 1, wn = wv & 1;
  const int fr = lane & 15, fq4 = lane >> 4;

  f32x4 acc[4][4];
#pragma unroll
  for (int mi = 0; mi < 4; ++mi)
#pragma unroll
    for (int ni = 0; ni < 4; ++ni) { f32x4 z = {0.f, 0.f, 0.f, 0.f}; acc[mi][ni] = z; }

  for (int kt = 0; kt < 16; ++kt) {
#pragma unroll
    for (int i = 0; i < 4; ++i) {
      int ci = i * 256 + t;
      int row = ci >> 3, c8 = ci & 7;
      gld16(A + (size_t)(bm * 128 + row) * 1024 + kt * 64 + c8 * 8,
            (char*)lA + (i * 256 + wv * 64) * 16);
      gld16(Wl + (size_t)(bn * 128 + row) * 1024 + kt * 64 + c8 * 8,
            (char*)lB + (i * 256 + wv * 64) * 16);
    }
    __syncthreads();
#pragma unroll
    for (int kk = 0; kk < 2; ++kk) {
      bf16x8 af[4], bfr[4];
#pragma unroll
      for (int mi = 0; mi < 4; ++mi)
        af[mi] = *(const bf16x8*)&lA[(wm * 64 + mi * 16 + fr) * 64 + kk * 32 + fq4 * 8];
#pragma unroll
      for (int ni = 0; ni < 4; ++ni)
        bfr[ni] = *(const bf16x8*)&lB[(wn * 64 + ni * 16 + fr) * 64 + kk * 32 + fq4 * 8];
#pragma unroll
      for (int mi = 0; mi < 4; ++mi)
#pragma unroll
        for (int ni = 0; ni < 4; ++ni)
          acc[mi][ni] = MFMA(af[mi], bfr[ni], acc[mi][ni]);
    }
    __syncthreads();
  }

  // LoRA as one extra MFMA K-step
  {
    int row = t >> 1, half = t & 1;
#pragma unroll
    for (int g = 0; g < 16; ++g) {
      lA[row * 64 + half * 16 + g] =
          half ? (__bf16)0.f : (__bf16)xavg[(bm * 128 + row) * 16 + g];
      lB[row * 64 + half * 16 + g] =
          half ? (__bf16)0.f : (__bf16)(20.f * dl[(bn * 128 + row) * 16 + g]);
    }
    __syncthreads();
    bf16x8 af[4], bfr[4];
#pragma unroll
    for (int mi = 0; mi < 4; ++mi)
      af[mi] = *(const bf16x8*)&lA[(wm * 64 + mi * 16 + fr) * 64 + fq4 * 8];
#pragma unroll
    for (int ni = 0; ni < 4; ++ni)
      bfr[ni] = *(const bf16x8*)&lB[(wn * 64 + ni * 16 + fr) * 64 + fq4 * 8];
#pragma unroll
    for (int mi = 0; mi < 4; ++mi)
#pragma unroll
      for (int ni = 0; ni < 4; ++ni)
        acc[mi][ni] = MFMA(af[mi], bfr[ni], acc[mi][ni]);
  }

  // q scale folds 1/sqrt(64) and log2(e) for the log2-domain softmax
  const float outmul =
      (mode == 0 && blockIdx.z == 0) ? 0.1f * 0.125f * 1.4426950408889634f : 0.1f;
#pragma unroll
  for (int mi = 0; mi < 4; ++mi)
#pragma unroll
    for (int ni = 0; ni < 4; ++ni) {
      int o = bn * 128 + wn * 64 + ni * 16 + fr;
      if (mode == 0 && blockIdx.z == 2) {
        // V^T: 4 consecutive n-columns of one row -> one 8B store
        int m0 = bm * 128 + wm * 64 + mi * 16 + fq4 * 4;
        int b = m0 >> 11, nr0 = m0 & 2047;
        int h = o >> 6, d = o & 63;
        __bf16 pk[4];
#pragma unroll
        for (int j = 0; j < 4; ++j) pk[j] = (__bf16)(acc[mi][ni][j] * outmul);
        *(uint2*)(vout + ((size_t)(b * 16 + h) * 64 + d) * 2048 + nr0) = *(uint2*)pk;
      } else {
#pragma unroll
        for (int j = 0; j < 4; ++j) {
          int m = bm * 128 + wm * 64 + mi * 16 + fq4 * 4 + j;
          float v = acc[mi][ni][j] * outmul;
          if (mode == 0) {
            int b = m >> 11, nr = m & 2047;
            int h = o >> 6, d = o & 63;
            if (blockIdx.z == 0)
              qout[((size_t)(b * 16 + h) * 2048 + nr) * 64 + d] = (__bf16)v;
            else
              kout[((size_t)(b * 16 + h) * 2048 + nr) * 64 + d] = (__bf16)v;
          } else {
            fout[(size_t)m * 1024 + o] = v;
          }
        }
      }
    }
}

// ---------------- flash attention (round 3) ----------------
// Log2-domain softmax, defer-max (m init 0; fallback only if logits grow by
// >8 in log2, never for this data), denominator via ones-column MFMA.
// Common path has ZERO cross-lane ops and zero rescale work.
__global__ __launch_bounds__(256) void k_attn(
    const __bf16* __restrict__ qb,   // [bh][n][64] (pre-scaled, log2 domain)
    const __bf16* __restrict__ kb,   // [bh][n][64]
    const __bf16* __restrict__ vbt,  // [bh][64][n]
    __bf16* __restrict__ attnb,      // [4096][1024]
    float* __restrict__ aavg) {      // [4096][16]
  __shared__ __align__(16) __bf16 lK[2][64 * 64];
  __shared__ __align__(16) __bf16 lVT[2][64 * 64];
  __shared__ __align__(16) __bf16 lP[4 * 16 * 64];

  const int t = threadIdx.x, lane = t & 63, wv = t >> 6;
  const int bh = blockIdx.y;
  const int qt = blockIdx.x;
  const int fr = lane & 15, fq4 = lane >> 4;
  const int qrow0 = qt * 64 + wv * 16;
  const size_t hbase = (size_t)bh * 2048 * 64;
  __bf16* lPw = lP + wv * 16 * 64;

  // staging coordinates (slot = 16B chunk), source pre-swizzled (rule #21)
  const int srow0 = t >> 3, sc0 = (t & 7) ^ (srow0 & 7);
  const int srow1 = (256 + t) >> 3, sc1 = (t & 7) ^ (srow1 & 7);
  const int dst0 = (wv * 64) * 16, dst1 = (256 + wv * 64) * 16;

  bf16x8 qf[2];
#pragma unroll
  for (int kk = 0; kk < 2; ++kk)
    qf[kk] = *(const bf16x8*)(qb + hbase + (size_t)(qrow0 + fr) * 64 + kk * 32 + fq4 * 8);

  bf16x8 vones;
#pragma unroll
  for (int e = 0; e < 8; ++e) vones[e] = (__bf16)1.0f;

  f32x4 o[4], o4;   // o4 = running softmax denominator (ones-column)
#pragma unroll
  for (int di = 0; di < 4; ++di) { f32x4 z = {0.f, 0.f, 0.f, 0.f}; o[di] = z; }
  { f32x4 z = {0.f, 0.f, 0.f, 0.f}; o4 = z; }
  float mrun[4] = {0.f, 0.f, 0.f, 0.f};   // log2-domain running max, init 0

  // prologue: stage tile 0 into buf 0
  gld16(kb + hbase + (size_t)(srow0)*64 + sc0 * 8, (char*)lK[0] + dst0);
  gld16(vbt + hbase + (size_t)srow0 * 2048 + sc0 * 8, (char*)lVT[0] + dst0);
  gld16(kb + hbase + (size_t)(srow1)*64 + sc1 * 8, (char*)lK[0] + dst1);
  gld16(vbt + hbase + (size_t)srow1 * 2048 + sc1 * 8, (char*)lVT[0] + dst1);
  __syncthreads();

  int cur = 0;
  for (int kt = 0; kt < 32; ++kt) {
    if (kt + 1 < 32) {
      int kn = (kt + 1) * 64;
      gld16(kb + hbase + (size_t)(kn + srow0) * 64 + sc0 * 8, (char*)lK[cur ^ 1] + dst0);
      gld16(vbt + hbase + (size_t)srow0 * 2048 + kn + sc0 * 8, (char*)lVT[cur ^ 1] + dst0);
      gld16(kb + hbase + (size_t)(kn + srow1) * 64 + sc1 * 8, (char*)lK[cur ^ 1] + dst1);
      gld16(vbt + hbase + (size_t)srow1 * 2048 + kn + sc1 * 8, (char*)lVT[cur ^ 1] + dst1);
    }

    // S = Q K^T (log2 domain)
    f32x4 s[4];
#pragma unroll
    for (int ni = 0; ni < 4; ++ni) { f32x4 z = {0.f, 0.f, 0.f, 0.f}; s[ni] = z; }
    __builtin_amdgcn_s_setprio(1);
#pragma unroll
    for (int kk = 0; kk < 2; ++kk)
#pragma unroll
      for (int ni = 0; ni < 4; ++ni) {
        bf16x8 kf = *(const bf16x8*)&lK[cur][(ni * 16 + fr) * 64 +
                                            (((kk << 2) | fq4) ^ (fr & 7)) * 8];
        s[ni] = MFMA(qf[kk], kf, s[ni]);
      }
    __builtin_amdgcn_s_setprio(0);

    // defer-max check (T13): lane-local max only, no shuffles in common path
    float pm[4];
#pragma unroll
    for (int j = 0; j < 4; ++j)
      pm[j] = fmaxf(fmaxf(s[0][j], s[1][j]), fmaxf(s[2][j], s[3][j]));
    bool ok = (pm[0] <= mrun[0] + 8.f) && (pm[1] <= mrun[1] + 8.f) &&
              (pm[2] <= mrun[2] + 8.f) && (pm[3] <= mrun[3] + 8.f);
    if (!__all(ok)) {   // rare path (never for this data): full rescale
#pragma unroll
      for (int j = 0; j < 4; ++j) {
        float rm = redmax16(pm[j]);
        float mnew = fmaxf(mrun[j], rm);
        float alpha = __builtin_amdgcn_exp2f(mrun[j] - mnew);
        mrun[j] = mnew;
        o4[j] *= alpha;
#pragma unroll
        for (int di = 0; di < 4; ++di) o[di][j] *= alpha;
      }
    }

    // P = exp2(s - m); write to wave-private swizzled lP
#pragma unroll
    for (int j = 0; j < 4; ++j) {
      int r = fq4 * 4 + j;
#pragma unroll
      for (int ni = 0; ni < 4; ++ni) {
        float p = __builtin_amdgcn_exp2f(s[ni][j] - mrun[j]);
        int chunk = ni * 2 + (fr >> 3);
        lPw[r * 64 + ((chunk ^ (r & 7)) << 3) + (fr & 7)] = (__bf16)p;
      }
    }

    // O += P V ; denominator += P @ ones  (same-wave DS ordering; no barrier)
    __builtin_amdgcn_s_setprio(1);
#pragma unroll
    for (int kk = 0; kk < 2; ++kk) {
      bf16x8 pa = *(const bf16x8*)&lPw[fr * 64 + (((kk << 2) | fq4) ^ (fr & 7)) * 8];
#pragma unroll
      for (int di = 0; di < 4; ++di) {
        bf16x8 vf = *(const bf16x8*)&lVT[cur][(di * 16 + fr) * 64 +
                                              (((kk << 2) | fq4) ^ (fr & 7)) * 8];
        o[di] = MFMA(pa, vf, o[di]);
      }
      o4 = MFMA(pa, vones, o4);
    }
    __builtin_amdgcn_s_setprio(0);

    __syncthreads();   // staging of kt+1 complete; buf[cur] free for kt+2
    cur ^= 1;
  }

  // epilogue: normalize by o4, write attn bf16 + per-row head mean (fp32)
  const int b = bh >> 4, h = bh & 15;
#pragma unroll
  for (int j = 0; j < 4; ++j) {
    float inv = 1.f / o4[j];
    int nr = qt * 64 + wv * 16 + fq4 * 4 + j;
    size_t mrow = ((size_t)(b * 2048 + nr)) * 1024 + h * 64;
    float rowsum = 0.f;
#pragma unroll
    for (int di = 0; di < 4; ++di) {
      float vv = o[di][j] * inv;
      attnb[mrow + di * 16 + fr] = (__bf16)vv;
      rowsum += vv;
    }
    rowsum = redsum16(rowsum);
    if (fr == 0) aavg[(size_t)(b * 2048 + nr) * 16 + h] = rowsum * (1.f / 64.f);
  }
}

// ---------------- launch ----------------
extern "C" void kernel_launch(void* const* d_in, const int* in_sizes, int n_in,
                              void* d_out, int out_size, void* d_ws, size_t ws_size,
                              hipStream_t stream) {
  const float* x = (const float*)d_in[0];
  const float* w_[4]  = {(const float*)d_in[1], (const float*)d_in[4],
                         (const float*)d_in[7], (const float*)d_in[10]};
  const float* dW_[4] = {(const float*)d_in[2], (const float*)d_in[5],
                         (const float*)d_in[8], (const float*)d_in[11]};
  const float* dB_[4] = {(const float*)d_in[3], (const float*)d_in[6],
                         (const float*)d_in[9], (const float*)d_in[12]};
  float* out = (float*)d_out;

  char* ws = (char*)d_ws;
  const size_t MB = 1ull << 20;
  __bf16* xbf   = (__bf16*)(ws);                 // 8 MB
  __bf16* wq    = (__bf16*)(ws + 8 * MB);        // 8 MB (4 layers)
  __bf16* qb    = (__bf16*)(ws + 16 * MB);       // 8 MB
  __bf16* kb    = (__bf16*)(ws + 24 * MB);       // 8 MB
  __bf16* vbt   = (__bf16*)(ws + 32 * MB);       // 8 MB
  __bf16* attnb = (__bf16*)(ws + 40 * MB);       // 8 MB
  float* xavg   = (float*)(ws + 48 * MB);                  // 256 KB
  float* aavg   = (float*)(ws + 48 * MB + 256 * 1024);     // 256 KB
  float* delta  = (float*)(ws + 48 * MB + 512 * 1024);     // 256 KB

  k_quant_w<<<4096, 256, 0, stream>>>(w_[0], w_[1], w_[2], w_[3], wq);
  k_xbf<<<4096, 256, 0, stream>>>(x, xbf);
  k_xavg<<<256, 256, 0, stream>>>(x, xavg);
  k_delta<<<256, 256, 0, stream>>>(dW_[0], dB_[0], dW_[1], dB_[1],
                                   dW_[2], dB_[2], dW_[3], dB_[3], delta);
  k_gemm<<<dim3(8, 32, 3), 256, 0, stream>>>(xbf, wq, delta, xavg,
                                             qb, kb, vbt, nullptr, 0, 0);
  k_attn<<<dim3(32, 32), 256, 0, stream>>>(qb, kb, vbt, attnb, aavg);
  k_gemm<<<dim3(8, 32, 1), 256, 0, stream>>>(attnb, wq, delta, aavg,
                                             nullptr, nullptr, nullptr, out, 1, 3);
}

// Round 4
// 168.214 us; speedup vs baseline: 1.6637x; 1.2098x over previous
//
#include <hip/hip_runtime.h>

// ---------------------------------------------------------------------------
// SelfAttention with QA-LoRA quantized projections, MI355X (gfx950)
// Round 4: attn P-in-register — swapped QK^T (MFMA(K,Q)) makes each lane hold
//          its q-row's P values; a bit-permutation of the PV contraction axis
//          (absorbed into V's LDS read pattern) lets pa fragments be built
//          with zero cross-lane ops. No lP buffer, no ds_write in the loop,
//          no max bookkeeping (analytic logit bound, m=0). LDS 32KB -> 5
//          blocks/CU. Also: fused x->bf16 + x_avg prep kernel.
// ---------------------------------------------------------------------------

typedef __bf16 bf16x8 __attribute__((ext_vector_type(8)));
typedef __bf16 bf16x4 __attribute__((ext_vector_type(4)));
typedef float f32x4 __attribute__((ext_vector_type(4)));

#define MFMA(a, b, c) __builtin_amdgcn_mfma_f32_16x16x32_bf16(a, b, c, 0, 0, 0)

__device__ __forceinline__ void gld16(const void* g, void* l) {
  __builtin_amdgcn_global_load_lds(
      (const __attribute__((address_space(1))) void*)g,
      (__attribute__((address_space(3))) void*)l, 16, 0, 0);
}

// fake_quantize: returns the clipped, round-half-even INTEGER (not dequantized).
__device__ __forceinline__ float fq(float v) {
  float q = rintf(v / 0.1f);           // v_rndne_f32: round half to even
  return fminf(fmaxf(q, -128.f), 127.f);
}

__device__ __forceinline__ float redsum16(float v) {
  v += __shfl_xor(v, 1);
  v += __shfl_xor(v, 2);
  v += __shfl_xor(v, 4);
  v += __shfl_xor(v, 8);
  return v;
}

// ---------------- prep kernels ----------------

__global__ __launch_bounds__(256) void k_quant_w(
    const float* __restrict__ w0, const float* __restrict__ w1,
    const float* __restrict__ w2, const float* __restrict__ w3,
    __bf16* __restrict__ wq) {
  int i = blockIdx.x * 256 + threadIdx.x;
  int layer = i >> 18;
  const float* src = (layer == 0) ? w0 : (layer == 1) ? w1 : (layer == 2) ? w2 : w3;
  float4 v = ((const float4*)src)[i & 262143];
  __bf16 r[4] = {(__bf16)fq(v.x), (__bf16)fq(v.y), (__bf16)fq(v.z), (__bf16)fq(v.w)};
  *(uint2*)(wq + ((size_t)i << 2)) = *(uint2*)r;
}

// fused: x fp32 -> bf16  AND  x_avg (64-elem group means). One read of x.
// One block = one row (1024 elems); thread t holds elems 4t..4t+3; group g
// = threads 16g..16g+15 -> 16-lane shfl reduce.
__global__ __launch_bounds__(256) void k_xprep(const float* __restrict__ x,
                                               __bf16* __restrict__ xbf,
                                               float* __restrict__ xavg) {
  int row = blockIdx.x, t = threadIdx.x;
  float4 v = ((const float4*)(x + (size_t)row * 1024))[t];
  __bf16 r[4] = {(__bf16)v.x, (__bf16)v.y, (__bf16)v.z, (__bf16)v.w};
  ((uint2*)(xbf + (size_t)row * 1024))[t] = *(uint2*)r;
  float s = v.x + v.y + v.z + v.w;
  s = redsum16(s);
  if ((t & 15) == 0) xavg[row * 16 + (t >> 4)] = s * (1.f / 64.f);
}

__global__ __launch_bounds__(256) void k_delta(
    const float* __restrict__ dW0, const float* __restrict__ dB0,
    const float* __restrict__ dW1, const float* __restrict__ dB1,
    const float* __restrict__ dW2, const float* __restrict__ dB2,
    const float* __restrict__ dW3, const float* __restrict__ dB3,
    float* __restrict__ delta) {
  int i = blockIdx.x * 256 + threadIdx.x;
  int layer = i >> 14, o = (i >> 4) & 1023, g = i & 15;
  const float* dW = (layer == 0) ? dW0 : (layer == 1) ? dW1 : (layer == 2) ? dW2 : dW3;
  const float* dB = (layer == 0) ? dB0 : (layer == 1) ? dB1 : (layer == 2) ? dB2 : dB3;
  float acc = 0.f;
#pragma unroll
  for (int r = 0; r < 32; ++r)
    acc += (0.1f * fq(dB[o * 32 + r])) * (0.1f * fq(dW[r * 16 + g]));
  delta[i] = acc;
}

// ---------------- GEMM (unchanged from round 3) ----------------
__global__ __launch_bounds__(256) void k_gemm(
    const __bf16* __restrict__ A,       // [4096][1024]
    const __bf16* __restrict__ Wq,      // [4][1024][1024] int codes
    const float* __restrict__ deltas,   // [4][1024][16]
    const float* __restrict__ xavg,     // [4096][16]
    __bf16* __restrict__ qout,          // [bh][n][64]
    __bf16* __restrict__ kout,          // [bh][n][64]
    __bf16* __restrict__ vout,          // [bh][64][n]
    float* __restrict__ fout,           // [4096][1024]
    int mode, int layer_base) {
  __shared__ __align__(16) __bf16 lA[128 * 64];
  __shared__ __align__(16) __bf16 lB[128 * 64];

  const int t = threadIdx.x;
  const int lane = t & 63;
  const int wv = t >> 6;
  const int bm = blockIdx.y;
  const int bn = blockIdx.x;
  const int layer = layer_base + blockIdx.z;
  const __bf16* Wl = Wq + ((size_t)layer << 20);
  const float* dl = deltas + (layer << 14);
  const int wm = wv >> 1, wn = wv & 1;
  const int fr = lane & 15, fq4 = lane >> 4;

  f32x4 acc[4][4];
#pragma unroll
  for (int mi = 0; mi < 4; ++mi)
#pragma unroll
    for (int ni = 0; ni < 4; ++ni) { f32x4 z = {0.f, 0.f, 0.f, 0.f}; acc[mi][ni] = z; }

  for (int kt = 0; kt < 16; ++kt) {
#pragma unroll
    for (int i = 0; i < 4; ++i) {
      int ci = i * 256 + t;
      int row = ci >> 3, c8 = ci & 7;
      gld16(A + (size_t)(bm * 128 + row) * 1024 + kt * 64 + c8 * 8,
            (char*)lA + (i * 256 + wv * 64) * 16);
      gld16(Wl + (size_t)(bn * 128 + row) * 1024 + kt * 64 + c8 * 8,
            (char*)lB + (i * 256 + wv * 64) * 16);
    }
    __syncthreads();
#pragma unroll
    for (int kk = 0; kk < 2; ++kk) {
      bf16x8 af[4], bfr[4];
#pragma unroll
      for (int mi = 0; mi < 4; ++mi)
        af[mi] = *(const bf16x8*)&lA[(wm * 64 + mi * 16 + fr) * 64 + kk * 32 + fq4 * 8];
#pragma unroll
      for (int ni = 0; ni < 4; ++ni)
        bfr[ni] = *(const bf16x8*)&lB[(wn * 64 + ni * 16 + fr) * 64 + kk * 32 + fq4 * 8];
#pragma unroll
      for (int mi = 0; mi < 4; ++mi)
#pragma unroll
        for (int ni = 0; ni < 4; ++ni)
          acc[mi][ni] = MFMA(af[mi], bfr[ni], acc[mi][ni]);
    }
    __syncthreads();
  }

  // LoRA as one extra MFMA K-step
  {
    int row = t >> 1, half = t & 1;
#pragma unroll
    for (int g = 0; g < 16; ++g) {
      lA[row * 64 + half * 16 + g] =
          half ? (__bf16)0.f : (__bf16)xavg[(bm * 128 + row) * 16 + g];
      lB[row * 64 + half * 16 + g] =
          half ? (__bf16)0.f : (__bf16)(20.f * dl[(bn * 128 + row) * 16 + g]);
    }
    __syncthreads();
    bf16x8 af[4], bfr[4];
#pragma unroll
    for (int mi = 0; mi < 4; ++mi)
      af[mi] = *(const bf16x8*)&lA[(wm * 64 + mi * 16 + fr) * 64 + fq4 * 8];
#pragma unroll
    for (int ni = 0; ni < 4; ++ni)
      bfr[ni] = *(const bf16x8*)&lB[(wn * 64 + ni * 16 + fr) * 64 + fq4 * 8];
#pragma unroll
    for (int mi = 0; mi < 4; ++mi)
#pragma unroll
      for (int ni = 0; ni < 4; ++ni)
        acc[mi][ni] = MFMA(af[mi], bfr[ni], acc[mi][ni]);
  }

  // q scale folds 1/sqrt(64) and log2(e) for the log2-domain softmax
  const float outmul =
      (mode == 0 && blockIdx.z == 0) ? 0.1f * 0.125f * 1.4426950408889634f : 0.1f;
#pragma unroll
  for (int mi = 0; mi < 4; ++mi)
#pragma unroll
    for (int ni = 0; ni < 4; ++ni) {
      int o = bn * 128 + wn * 64 + ni * 16 + fr;
      if (mode == 0 && blockIdx.z == 2) {
        // V^T: 4 consecutive n-columns of one row -> one 8B store
        int m0 = bm * 128 + wm * 64 + mi * 16 + fq4 * 4;
        int b = m0 >> 11, nr0 = m0 & 2047;
        int h = o >> 6, d = o & 63;
        __bf16 pk[4];
#pragma unroll
        for (int j = 0; j < 4; ++j) pk[j] = (__bf16)(acc[mi][ni][j] * outmul);
        *(uint2*)(vout + ((size_t)(b * 16 + h) * 64 + d) * 2048 + nr0) = *(uint2*)pk;
      } else {
#pragma unroll
        for (int j = 0; j < 4; ++j) {
          int m = bm * 128 + wm * 64 + mi * 16 + fq4 * 4 + j;
          float v = acc[mi][ni][j] * outmul;
          if (mode == 0) {
            int b = m >> 11, nr = m & 2047;
            int h = o >> 6, d = o & 63;
            if (blockIdx.z == 0)
              qout[((size_t)(b * 16 + h) * 2048 + nr) * 64 + d] = (__bf16)v;
            else
              kout[((size_t)(b * 16 + h) * 2048 + nr) * 64 + d] = (__bf16)v;
          } else {
            fout[(size_t)m * 1024 + o] = v;
          }
        }
      }
    }
}

// ---------------- flash attention (round 4) ----------------
// Swapped QK^T: s[ni] = MFMA(kf, qf) gives lane (fr,g) -> S[q=fr][key=16ni+4g+j].
// PV contraction axis permuted by pi(slot=8g+e) = 32kk + 16(e>>2) + 4g + (e&3)
// (bijective bit shuffle): pa[kk][e] = exp2(s[2kk+(e>>2)][e&3]) is lane-local;
// V-frag reads two b64s per (kk,di) at columns 4g.. and 4g+16.. (xor-swizzled).
// Denominator via ones-column MFMA (pi-invariant). No max tracking (|logit|
// analytically << exp2 range in log2 domain).
__global__ __launch_bounds__(256) void k_attn(
    const __bf16* __restrict__ qb,   // [bh][n][64] (pre-scaled, log2 domain)
    const __bf16* __restrict__ kb,   // [bh][n][64]
    const __bf16* __restrict__ vbt,  // [bh][64][n]
    __bf16* __restrict__ attnb,      // [4096][1024]
    float* __restrict__ aavg) {      // [4096][16]
  __shared__ __align__(16) __bf16 lK[2][64 * 64];
  __shared__ __align__(16) __bf16 lVT[2][64 * 64];

  const int t = threadIdx.x, lane = t & 63, wv = t >> 6;
  const int bh = blockIdx.y;
  const int qt = blockIdx.x;
  const int fr = lane & 15, g = lane >> 4;
  const int qrow0 = qt * 64 + wv * 16;
  const size_t hbase = (size_t)bh * 2048 * 64;

  // staging coordinates (slot = 16B chunk), source pre-swizzled (rule #21)
  const int srow0 = t >> 3, sc0 = (t & 7) ^ (srow0 & 7);
  const int srow1 = (256 + t) >> 3, sc1 = (t & 7) ^ (srow1 & 7);
  const int dst0 = (wv * 64) * 16, dst1 = (256 + wv * 64) * 16;

  bf16x8 qf[2];
#pragma unroll
  for (int kk = 0; kk < 2; ++kk)
    qf[kk] = *(const bf16x8*)(qb + hbase + (size_t)(qrow0 + fr) * 64 + kk * 32 + g * 8);

  bf16x8 vones;
#pragma unroll
  for (int e = 0; e < 8; ++e) vones[e] = (__bf16)1.0f;

  f32x4 o[4], o4;   // o4 = running softmax denominator (ones-column)
#pragma unroll
  for (int di = 0; di < 4; ++di) { f32x4 z = {0.f, 0.f, 0.f, 0.f}; o[di] = z; }
  { f32x4 z = {0.f, 0.f, 0.f, 0.f}; o4 = z; }

  // prologue: stage tile 0 into buf 0
  gld16(kb + hbase + (size_t)(srow0)*64 + sc0 * 8, (char*)lK[0] + dst0);
  gld16(vbt + hbase + (size_t)srow0 * 2048 + sc0 * 8, (char*)lVT[0] + dst0);
  gld16(kb + hbase + (size_t)(srow1)*64 + sc1 * 8, (char*)lK[0] + dst1);
  gld16(vbt + hbase + (size_t)srow1 * 2048 + sc1 * 8, (char*)lVT[0] + dst1);
  __syncthreads();

  int cur = 0;
  for (int kt = 0; kt < 32; ++kt) {
    if (kt + 1 < 32) {
      int kn = (kt + 1) * 64;
      gld16(kb + hbase + (size_t)(kn + srow0) * 64 + sc0 * 8, (char*)lK[cur ^ 1] + dst0);
      gld16(vbt + hbase + (size_t)srow0 * 2048 + kn + sc0 * 8, (char*)lVT[cur ^ 1] + dst0);
      gld16(kb + hbase + (size_t)(kn + srow1) * 64 + sc1 * 8, (char*)lK[cur ^ 1] + dst1);
      gld16(vbt + hbase + (size_t)srow1 * 2048 + kn + sc1 * 8, (char*)lVT[cur ^ 1] + dst1);
    }

    // S^T = K Q^T (log2 domain): s[ni][j] = S[q=fr][key=16ni+4g+j]
    f32x4 s[4];
#pragma unroll
    for (int ni = 0; ni < 4; ++ni) { f32x4 z = {0.f, 0.f, 0.f, 0.f}; s[ni] = z; }
    __builtin_amdgcn_s_setprio(1);
#pragma unroll
    for (int kk = 0; kk < 2; ++kk)
#pragma unroll
      for (int ni = 0; ni < 4; ++ni) {
        bf16x8 kf = *(const bf16x8*)&lK[cur][(ni * 16 + fr) * 64 +
                                            (((kk << 2) | g) ^ (fr & 7)) * 8];
        s[ni] = MFMA(kf, qf[kk], s[ni]);
      }
    __builtin_amdgcn_s_setprio(0);

    // P = exp2(S), packed directly into MFMA A-fragments (all lane-local)
    bf16x8 pa[2];
#pragma unroll
    for (int kk = 0; kk < 2; ++kk)
#pragma unroll
      for (int e = 0; e < 8; ++e)
        pa[kk][e] = (__bf16)__builtin_amdgcn_exp2f(s[2 * kk + (e >> 2)][e & 3]);

    // O += P V ; denominator += P @ ones  (keys permuted consistently)
    __builtin_amdgcn_s_setprio(1);
#pragma unroll
    for (int kk = 0; kk < 2; ++kk) {
#pragma unroll
      for (int di = 0; di < 4; ++di) {
        int base = (di * 16 + fr) * 64;
        int ch = ((kk << 2) | (g >> 1)) ^ (fr & 7);
        bf16x4 vlo = *(const bf16x4*)&lVT[cur][base + ch * 8 + (g & 1) * 4];
        bf16x4 vhi = *(const bf16x4*)&lVT[cur][base + (ch ^ 2) * 8 + (g & 1) * 4];
        bf16x8 vf;
#pragma unroll
        for (int e = 0; e < 4; ++e) { vf[e] = vlo[e]; vf[e + 4] = vhi[e]; }
        o[di] = MFMA(pa[kk], vf, o[di]);
      }
      o4 = MFMA(pa[kk], vones, o4);
    }
    __builtin_amdgcn_s_setprio(0);

    __syncthreads();   // staging of kt+1 complete; buf[cur] free for kt+2
    cur ^= 1;
  }

  // epilogue: normalize by o4, write attn bf16 + per-row head mean (fp32)
  const int b = bh >> 4, h = bh & 15;
#pragma unroll
  for (int j = 0; j < 4; ++j) {
    float inv = 1.f / o4[j];
    int nr = qt * 64 + wv * 16 + g * 4 + j;
    size_t mrow = ((size_t)(b * 2048 + nr)) * 1024 + h * 64;
    float rowsum = 0.f;
#pragma unroll
    for (int di = 0; di < 4; ++di) {
      float vv = o[di][j] * inv;
      attnb[mrow + di * 16 + fr] = (__bf16)vv;
      rowsum += vv;
    }
    rowsum = redsum16(rowsum);
    if (fr == 0) aavg[(size_t)(b * 2048 + nr) * 16 + h] = rowsum * (1.f / 64.f);
  }
}

// ---------------- launch ----------------
extern "C" void kernel_launch(void* const* d_in, const int* in_sizes, int n_in,
                              void* d_out, int out_size, void* d_ws, size_t ws_size,
                              hipStream_t stream) {
  const float* x = (const float*)d_in[0];
  const float* w_[4]  = {(const float*)d_in[1], (const float*)d_in[4],
                         (const float*)d_in[7], (const float*)d_in[10]};
  const float* dW_[4] = {(const float*)d_in[2], (const float*)d_in[5],
                         (const float*)d_in[8], (const float*)d_in[11]};
  const float* dB_[4] = {(const float*)d_in[3], (const float*)d_in[6],
                         (const float*)d_in[9], (const float*)d_in[12]};
  float* out = (float*)d_out;

  char* ws = (char*)d_ws;
  const size_t MB = 1ull << 20;
  __bf16* xbf   = (__bf16*)(ws);                 // 8 MB
  __bf16* wq    = (__bf16*)(ws + 8 * MB);        // 8 MB (4 layers)
  __bf16* qb    = (__bf16*)(ws + 16 * MB);       // 8 MB
  __bf16* kb    = (__bf16*)(ws + 24 * MB);       // 8 MB
  __bf16* vbt   = (__bf16*)(ws + 32 * MB);       // 8 MB
  __bf16* attnb = (__bf16*)(ws + 40 * MB);       // 8 MB
  float* xavg   = (float*)(ws + 48 * MB);                  // 256 KB
  float* aavg   = (float*)(ws + 48 * MB + 256 * 1024);     // 256 KB
  float* delta  = (float*)(ws + 48 * MB + 512 * 1024);     // 256 KB

  k_quant_w<<<4096, 256, 0, stream>>>(w_[0], w_[1], w_[2], w_[3], wq);
  k_xprep<<<4096, 256, 0, stream>>>(x, xbf, xavg);
  k_delta<<<256, 256, 0, stream>>>(dW_[0], dB_[0], dW_[1], dB_[1],
                                   dW_[2], dB_[2], dW_[3], dB_[3], delta);
  k_gemm<<<dim3(8, 32, 3), 256, 0, stream>>>(xbf, wq, delta, xavg,
                                             qb, kb, vbt, nullptr, 0, 0);
  k_attn<<<dim3(32, 32), 256, 0, stream>>>(qb, kb, vbt, attnb, aavg);
  k_gemm<<<dim3(8, 32, 1), 256, 0, stream>>>(attnb, wq, delta, aavg,
                                             nullptr, nullptr, nullptr, out, 1, 3);
}

// Round 5
// 151.988 us; speedup vs baseline: 1.8414x; 1.1068x over previous
//
#include <hip/hip_runtime.h>

// ---------------------------------------------------------------------------
// SelfAttention with QA-LoRA quantized projections, MI355X (gfx950)
// Round 5: GEMM prefetch double-buffer (T3-minimal, one barrier/K-tile),
//          LDS XOR swizzle on GEMM tiles (T2), LoRA folded as a K-extension
//          (A/W stride 1088: cols 1024..1039 = x_avg / 20*delta, rest 0) so
//          the rank-16 path is an ordinary 17th K-tile. Attn row-means are
//          written directly into attnb's extension columns.
// ---------------------------------------------------------------------------

typedef __bf16 bf16x8 __attribute__((ext_vector_type(8)));
typedef __bf16 bf16x4 __attribute__((ext_vector_type(4)));
typedef float f32x4 __attribute__((ext_vector_type(4)));

#define MFMA(a, b, c) __builtin_amdgcn_mfma_f32_16x16x32_bf16(a, b, c, 0, 0, 0)

#define KEXT 1088   // 1024 + 64 extension cols (16 LoRA + 48 zeros)

__device__ __forceinline__ void gld16(const void* g, void* l) {
  __builtin_amdgcn_global_load_lds(
      (const __attribute__((address_space(1))) void*)g,
      (__attribute__((address_space(3))) void*)l, 16, 0, 0);
}

// fake_quantize: returns the clipped, round-half-even INTEGER (not dequantized).
__device__ __forceinline__ float fq(float v) {
  float q = rintf(v / 0.1f);           // v_rndne_f32: round half to even
  return fminf(fmaxf(q, -128.f), 127.f);
}

__device__ __forceinline__ float redsum16(float v) {
  v += __shfl_xor(v, 1);
  v += __shfl_xor(v, 2);
  v += __shfl_xor(v, 4);
  v += __shfl_xor(v, 8);
  return v;
}

// ---------------- prep kernels ----------------

// weights -> bf16 int codes into stride-1088 layout
__global__ __launch_bounds__(256) void k_quant_w(
    const float* __restrict__ w0, const float* __restrict__ w1,
    const float* __restrict__ w2, const float* __restrict__ w3,
    __bf16* __restrict__ wq) {
  int i = blockIdx.x * 256 + threadIdx.x;          // 4 * 1024 * 256
  int layer = i >> 18, rest = i & 262143;
  int o = rest >> 8, c4 = rest & 255;
  const float* src = (layer == 0) ? w0 : (layer == 1) ? w1 : (layer == 2) ? w2 : w3;
  float4 v = ((const float4*)src)[rest];
  __bf16 r[4] = {(__bf16)fq(v.x), (__bf16)fq(v.y), (__bf16)fq(v.z), (__bf16)fq(v.w)};
  *(uint2*)(wq + (size_t)((layer << 10) | o) * KEXT + (c4 << 2)) = *(uint2*)r;
}

// fused: x fp32 -> bf16 (stride 1088) AND extension cols = group means.
__global__ __launch_bounds__(256) void k_xprep(const float* __restrict__ x,
                                               __bf16* __restrict__ xbf) {
  int row = blockIdx.x, t = threadIdx.x;
  float4 v = ((const float4*)(x + (size_t)row * 1024))[t];
  __bf16 r[4] = {(__bf16)v.x, (__bf16)v.y, (__bf16)v.z, (__bf16)v.w};
  *(uint2*)(xbf + (size_t)row * KEXT + 4 * t) = *(uint2*)r;
  float s = v.x + v.y + v.z + v.w;
  s = redsum16(s);                                  // all 16 lanes of group hold sum
  int g = t >> 4, j = t & 15;
  __bf16* ext = xbf + (size_t)row * KEXT + 1024;
  if (j == 0) ext[g] = (__bf16)(s * (1.f / 64.f));
  else if (j < 4) ext[16 + g * 3 + (j - 1)] = (__bf16)0.f;   // zero cols 1040..1087
}

// LoRA delta -> extension cols of wq: wq_ext[o][g] = bf16(20 * dBq@dWq * 0.01)
__global__ __launch_bounds__(256) void k_delta(
    const float* __restrict__ dW0, const float* __restrict__ dB0,
    const float* __restrict__ dW1, const float* __restrict__ dB1,
    const float* __restrict__ dW2, const float* __restrict__ dB2,
    const float* __restrict__ dW3, const float* __restrict__ dB3,
    __bf16* __restrict__ wq) {
  int i = blockIdx.x * 256 + threadIdx.x;          // 65536 = 4*1024*16
  int layer = i >> 14, o = (i >> 4) & 1023, g = i & 15;
  const float* dW = (layer == 0) ? dW0 : (layer == 1) ? dW1 : (layer == 2) ? dW2 : dW3;
  const float* dB = (layer == 0) ? dB0 : (layer == 1) ? dB1 : (layer == 2) ? dB2 : dB3;
  float acc = 0.f;
#pragma unroll
  for (int r = 0; r < 32; ++r)
    acc += (0.1f * fq(dB[o * 32 + r])) * (0.1f * fq(dW[r * 16 + g]));
  __bf16* ext = wq + (size_t)((layer << 10) | o) * KEXT + 1024;
  ext[g] = (__bf16)(20.f * acc);
#pragma unroll
  for (int k = 0; k < 3; ++k) ext[16 + g * 3 + k] = (__bf16)0.f;
}

// ---------------- GEMM (round 5: prefetch dbuf + swizzle + K-ext) ----------
// y = 0.1 * (A_ext @ W_ext^T) over K'=1088; 128x128 tile, BK=64, 4 waves.
// mode 0: z selects Q/K/V outputs (bf16). mode 1: fp32 to d_out.
__global__ __launch_bounds__(256) void k_gemm(
    const __bf16* __restrict__ A,       // [4096][1088]
    const __bf16* __restrict__ Wq,      // [4][1024][1088]
    __bf16* __restrict__ qout,          // [bh][n][64]
    __bf16* __restrict__ kout,          // [bh][n][64]
    __bf16* __restrict__ vout,          // [bh][64][n]
    float* __restrict__ fout,           // [4096][1024]
    int mode, int layer_base) {
  __shared__ __align__(16) __bf16 lA[2][128 * 64];
  __shared__ __align__(16) __bf16 lB[2][128 * 64];

  const int t = threadIdx.x;
  const int lane = t & 63;
  const int wv = t >> 6;
  const int bm = blockIdx.y;
  const int bn = blockIdx.x;
  const int layer = layer_base + blockIdx.z;
  const __bf16* Wl = Wq + (size_t)layer * 1024 * KEXT;
  const int wm = wv >> 1, wn = wv & 1;
  const int fr = lane & 15, fq4 = lane >> 4;

  // staging coords: thread t stages 4 chunks per matrix; same swizzled col
  // for all 4 (rows differ by 32 == 0 mod 8). Source pre-swizzled (rule #21).
  const int tr = t >> 3;                      // row within 32-row group
  const int scol = ((t & 7) ^ (tr & 7)) * 8;  // swizzled element offset

  f32x4 acc[4][4];
#pragma unroll
  for (int mi = 0; mi < 4; ++mi)
#pragma unroll
    for (int ni = 0; ni < 4; ++ni) { f32x4 z = {0.f, 0.f, 0.f, 0.f}; acc[mi][ni] = z; }

#define STAGE(kt, buf)                                                         \
  {                                                                            \
    _Pragma("unroll") for (int i = 0; i < 4; ++i) {                            \
      int row = i * 32 + tr;                                                   \
      gld16(A + (size_t)(bm * 128 + row) * KEXT + (kt)*64 + scol,              \
            (char*)lA[buf] + (i * 256 + wv * 64) * 16);                        \
      gld16(Wl + (size_t)(bn * 128 + row) * KEXT + (kt)*64 + scol,             \
            (char*)lB[buf] + (i * 256 + wv * 64) * 16);                        \
    }                                                                          \
  }

  STAGE(0, 0);
  __syncthreads();

  int cur = 0;
  for (int kt = 0; kt < 17; ++kt) {
    if (kt + 1 < 17) STAGE(kt + 1, cur ^ 1);
#pragma unroll
    for (int kk = 0; kk < 2; ++kk) {
      bf16x8 af[4], bfr[4];
#pragma unroll
      for (int mi = 0; mi < 4; ++mi)
        af[mi] = *(const bf16x8*)&lA[cur][(wm * 64 + mi * 16 + fr) * 64 +
                                          (((kk << 2) | fq4) ^ (fr & 7)) * 8];
#pragma unroll
      for (int ni = 0; ni < 4; ++ni)
        bfr[ni] = *(const bf16x8*)&lB[cur][(wn * 64 + ni * 16 + fr) * 64 +
                                           (((kk << 2) | fq4) ^ (fr & 7)) * 8];
#pragma unroll
      for (int mi = 0; mi < 4; ++mi)
#pragma unroll
        for (int ni = 0; ni < 4; ++ni)
          acc[mi][ni] = MFMA(af[mi], bfr[ni], acc[mi][ni]);
    }
    __syncthreads();   // drains vmcnt(0): next tile staged; buf[cur] reusable
    cur ^= 1;
  }
#undef STAGE

  // q scale folds 0.1 (dequant), 1/sqrt(64), log2(e) for log2-domain softmax
  const float outmul =
      (mode == 0 && blockIdx.z == 0) ? 0.1f * 0.125f * 1.4426950408889634f : 0.1f;
#pragma unroll
  for (int mi = 0; mi < 4; ++mi)
#pragma unroll
    for (int ni = 0; ni < 4; ++ni) {
      int o = bn * 128 + wn * 64 + ni * 16 + fr;
      if (mode == 0 && blockIdx.z == 2) {
        // V^T: 4 consecutive n-columns of one row -> one 8B store
        int m0 = bm * 128 + wm * 64 + mi * 16 + fq4 * 4;
        int b = m0 >> 11, nr0 = m0 & 2047;
        int h = o >> 6, d = o & 63;
        __bf16 pk[4];
#pragma unroll
        for (int j = 0; j < 4; ++j) pk[j] = (__bf16)(acc[mi][ni][j] * outmul);
        *(uint2*)(vout + ((size_t)(b * 16 + h) * 64 + d) * 2048 + nr0) = *(uint2*)pk;
      } else {
#pragma unroll
        for (int j = 0; j < 4; ++j) {
          int m = bm * 128 + wm * 64 + mi * 16 + fq4 * 4 + j;
          float v = acc[mi][ni][j] * outmul;
          if (mode == 0) {
            int b = m >> 11, nr = m & 2047;
            int h = o >> 6, d = o & 63;
            if (blockIdx.z == 0)
              qout[((size_t)(b * 16 + h) * 2048 + nr) * 64 + d] = (__bf16)v;
            else
              kout[((size_t)(b * 16 + h) * 2048 + nr) * 64 + d] = (__bf16)v;
          } else {
            fout[(size_t)m * 1024 + o] = v;
          }
        }
      }
    }
}

// ---------------- flash attention (round 4 structure, ext-col output) ------
__global__ __launch_bounds__(256) void k_attn(
    const __bf16* __restrict__ qb,   // [bh][n][64] (pre-scaled, log2 domain)
    const __bf16* __restrict__ kb,   // [bh][n][64]
    const __bf16* __restrict__ vbt,  // [bh][64][n]
    __bf16* __restrict__ attnb) {    // [4096][1088] (ext cols = head means)
  __shared__ __align__(16) __bf16 lK[2][64 * 64];
  __shared__ __align__(16) __bf16 lVT[2][64 * 64];

  const int t = threadIdx.x, lane = t & 63, wv = t >> 6;
  const int bh = blockIdx.y;
  const int qt = blockIdx.x;
  const int fr = lane & 15, g = lane >> 4;
  const int qrow0 = qt * 64 + wv * 16;
  const size_t hbase = (size_t)bh * 2048 * 64;

  const int srow0 = t >> 3, sc0 = (t & 7) ^ (srow0 & 7);
  const int srow1 = (256 + t) >> 3, sc1 = (t & 7) ^ (srow1 & 7);
  const int dst0 = (wv * 64) * 16, dst1 = (256 + wv * 64) * 16;

  bf16x8 qf[2];
#pragma unroll
  for (int kk = 0; kk < 2; ++kk)
    qf[kk] = *(const bf16x8*)(qb + hbase + (size_t)(qrow0 + fr) * 64 + kk * 32 + g * 8);

  bf16x8 vones;
#pragma unroll
  for (int e = 0; e < 8; ++e) vones[e] = (__bf16)1.0f;

  f32x4 o[4], o4;
#pragma unroll
  for (int di = 0; di < 4; ++di) { f32x4 z = {0.f, 0.f, 0.f, 0.f}; o[di] = z; }
  { f32x4 z = {0.f, 0.f, 0.f, 0.f}; o4 = z; }

  gld16(kb + hbase + (size_t)(srow0)*64 + sc0 * 8, (char*)lK[0] + dst0);
  gld16(vbt + hbase + (size_t)srow0 * 2048 + sc0 * 8, (char*)lVT[0] + dst0);
  gld16(kb + hbase + (size_t)(srow1)*64 + sc1 * 8, (char*)lK[0] + dst1);
  gld16(vbt + hbase + (size_t)srow1 * 2048 + sc1 * 8, (char*)lVT[0] + dst1);
  __syncthreads();

  int cur = 0;
  for (int kt = 0; kt < 32; ++kt) {
    if (kt + 1 < 32) {
      int kn = (kt + 1) * 64;
      gld16(kb + hbase + (size_t)(kn + srow0) * 64 + sc0 * 8, (char*)lK[cur ^ 1] + dst0);
      gld16(vbt + hbase + (size_t)srow0 * 2048 + kn + sc0 * 8, (char*)lVT[cur ^ 1] + dst0);
      gld16(kb + hbase + (size_t)(kn + srow1) * 64 + sc1 * 8, (char*)lK[cur ^ 1] + dst1);
      gld16(vbt + hbase + (size_t)srow1 * 2048 + kn + sc1 * 8, (char*)lVT[cur ^ 1] + dst1);
    }

    // S^T = K Q^T (log2 domain): s[ni][j] = S[q=fr][key=16ni+4g+j]
    f32x4 s[4];
#pragma unroll
    for (int ni = 0; ni < 4; ++ni) { f32x4 z = {0.f, 0.f, 0.f, 0.f}; s[ni] = z; }
    __builtin_amdgcn_s_setprio(1);
#pragma unroll
    for (int kk = 0; kk < 2; ++kk)
#pragma unroll
      for (int ni = 0; ni < 4; ++ni) {
        bf16x8 kf = *(const bf16x8*)&lK[cur][(ni * 16 + fr) * 64 +
                                            (((kk << 2) | g) ^ (fr & 7)) * 8];
        s[ni] = MFMA(kf, qf[kk], s[ni]);
      }
    __builtin_amdgcn_s_setprio(0);

    // P = exp2(S), packed directly into MFMA A-fragments (lane-local)
    bf16x8 pa[2];
#pragma unroll
    for (int kk = 0; kk < 2; ++kk)
#pragma unroll
      for (int e = 0; e < 8; ++e)
        pa[kk][e] = (__bf16)__builtin_amdgcn_exp2f(s[2 * kk + (e >> 2)][e & 3]);

    // O += P V ; denominator += P @ ones (contraction-axis permutation)
    __builtin_amdgcn_s_setprio(1);
#pragma unroll
    for (int kk = 0; kk < 2; ++kk) {
#pragma unroll
      for (int di = 0; di < 4; ++di) {
        int base = (di * 16 + fr) * 64;
        int ch = ((kk << 2) | (g >> 1)) ^ (fr & 7);
        bf16x4 vlo = *(const bf16x4*)&lVT[cur][base + ch * 8 + (g & 1) * 4];
        bf16x4 vhi = *(const bf16x4*)&lVT[cur][base + (ch ^ 2) * 8 + (g & 1) * 4];
        bf16x8 vf;
#pragma unroll
        for (int e = 0; e < 4; ++e) { vf[e] = vlo[e]; vf[e + 4] = vhi[e]; }
        o[di] = MFMA(pa[kk], vf, o[di]);
      }
      o4 = MFMA(pa[kk], vones, o4);
    }
    __builtin_amdgcn_s_setprio(0);

    __syncthreads();
    cur ^= 1;
  }

  // epilogue: normalize, write attn bf16 into stride-1088 rows + ext cols
  const int b = bh >> 4, h = bh & 15;
#pragma unroll
  for (int j = 0; j < 4; ++j) {
    float inv = 1.f / o4[j];
    int nr = qt * 64 + wv * 16 + g * 4 + j;
    size_t rowbase = (size_t)(b * 2048 + nr) * KEXT;
    float rowsum = 0.f;
#pragma unroll
    for (int di = 0; di < 4; ++di) {
      float vv = o[di][j] * inv;
      attnb[rowbase + h * 64 + di * 16 + fr] = (__bf16)vv;
      rowsum += vv;
    }
    rowsum = redsum16(rowsum);
    if (fr == 0) attnb[rowbase + 1024 + h] = (__bf16)(rowsum * (1.f / 64.f));
    if (h < 3) attnb[rowbase + 1040 + h * 16 + fr] = (__bf16)0.f;  // zero pad cols
  }
}

// ---------------- launch ----------------
extern "C" void kernel_launch(void* const* d_in, const int* in_sizes, int n_in,
                              void* d_out, int out_size, void* d_ws, size_t ws_size,
                              hipStream_t stream) {
  const float* x = (const float*)d_in[0];
  const float* w_[4]  = {(const float*)d_in[1], (const float*)d_in[4],
                         (const float*)d_in[7], (const float*)d_in[10]};
  const float* dW_[4] = {(const float*)d_in[2], (const float*)d_in[5],
                         (const float*)d_in[8], (const float*)d_in[11]};
  const float* dB_[4] = {(const float*)d_in[3], (const float*)d_in[6],
                         (const float*)d_in[9], (const float*)d_in[12]};
  float* out = (float*)d_out;

  char* ws = (char*)d_ws;
  const size_t MB = 1ull << 20;
  __bf16* xbf   = (__bf16*)(ws);                 // 4096*1088*2 = 8.9 MB
  __bf16* attnb = xbf;                           // alias: xbf dead after QKV GEMM
  __bf16* wq    = (__bf16*)(ws + 9 * MB);        // 4*1024*1088*2 = 8.9 MB
  __bf16* qb    = (__bf16*)(ws + 18 * MB);       // 8 MB
  __bf16* kb    = (__bf16*)(ws + 26 * MB);       // 8 MB
  __bf16* vbt   = (__bf16*)(ws + 34 * MB);       // 8 MB -> ends 42 MB

  k_quant_w<<<4096, 256, 0, stream>>>(w_[0], w_[1], w_[2], w_[3], wq);
  k_xprep<<<4096, 256, 0, stream>>>(x, xbf);
  k_delta<<<256, 256, 0, stream>>>(dW_[0], dB_[0], dW_[1], dB_[1],
                                   dW_[2], dB_[2], dW_[3], dB_[3], wq);
  k_gemm<<<dim3(8, 32, 3), 256, 0, stream>>>(xbf, wq, qb, kb, vbt, nullptr, 0, 0);
  k_attn<<<dim3(32, 32), 256, 0, stream>>>(qb, kb, vbt, attnb);
  k_gemm<<<dim3(8, 32, 1), 256, 0, stream>>>(attnb, wq, nullptr, nullptr, nullptr,
                                             out, 1, 3);
}

// Round 6
// 147.458 us; speedup vs baseline: 1.8979x; 1.0307x over previous
//
#include <hip/hip_runtime.h>

// ---------------------------------------------------------------------------
// SelfAttention with QA-LoRA quantized projections, MI355X (gfx950)
// Round 6: attn PV single-b128 via sigma-permuted V^T key layout (written by
//          the V-GEMM epilogue), QBLK=128 (32 q-rows/wave, kf/vf LDS reads
//          shared across two q-sets). GEMM/prep otherwise unchanged.
// ---------------------------------------------------------------------------

typedef __bf16 bf16x8 __attribute__((ext_vector_type(8)));
typedef float f32x4 __attribute__((ext_vector_type(4)));

#define MFMA(a, b, c) __builtin_amdgcn_mfma_f32_16x16x32_bf16(a, b, c, 0, 0, 0)

#define KEXT 1088   // 1024 + 64 extension cols (16 LoRA + 48 zeros)

__device__ __forceinline__ void gld16(const void* g, void* l) {
  __builtin_amdgcn_global_load_lds(
      (const __attribute__((address_space(1))) void*)g,
      (__attribute__((address_space(3))) void*)l, 16, 0, 0);
}

// fake_quantize: returns the clipped, round-half-even INTEGER (not dequantized).
__device__ __forceinline__ float fq(float v) {
  float q = rintf(v / 0.1f);           // v_rndne_f32: round half to even
  return fminf(fmaxf(q, -128.f), 127.f);
}

__device__ __forceinline__ float redsum16(float v) {
  v += __shfl_xor(v, 1);
  v += __shfl_xor(v, 2);
  v += __shfl_xor(v, 4);
  v += __shfl_xor(v, 8);
  return v;
}

// ---------------- prep kernels ----------------

// weights -> bf16 int codes into stride-1088 layout
__global__ __launch_bounds__(256) void k_quant_w(
    const float* __restrict__ w0, const float* __restrict__ w1,
    const float* __restrict__ w2, const float* __restrict__ w3,
    __bf16* __restrict__ wq) {
  int i = blockIdx.x * 256 + threadIdx.x;          // 4 * 1024 * 256
  int layer = i >> 18, rest = i & 262143;
  int o = rest >> 8, c4 = rest & 255;
  const float* src = (layer == 0) ? w0 : (layer == 1) ? w1 : (layer == 2) ? w2 : w3;
  float4 v = ((const float4*)src)[rest];
  __bf16 r[4] = {(__bf16)fq(v.x), (__bf16)fq(v.y), (__bf16)fq(v.z), (__bf16)fq(v.w)};
  *(uint2*)(wq + (size_t)((layer << 10) | o) * KEXT + (c4 << 2)) = *(uint2*)r;
}

// fused: x fp32 -> bf16 (stride 1088) AND extension cols = group means.
__global__ __launch_bounds__(256) void k_xprep(const float* __restrict__ x,
                                               __bf16* __restrict__ xbf) {
  int row = blockIdx.x, t = threadIdx.x;
  float4 v = ((const float4*)(x + (size_t)row * 1024))[t];
  __bf16 r[4] = {(__bf16)v.x, (__bf16)v.y, (__bf16)v.z, (__bf16)v.w};
  *(uint2*)(xbf + (size_t)row * KEXT + 4 * t) = *(uint2*)r;
  float s = v.x + v.y + v.z + v.w;
  s = redsum16(s);                                  // all 16 lanes of group hold sum
  int g = t >> 4, j = t & 15;
  __bf16* ext = xbf + (size_t)row * KEXT + 1024;
  if (j == 0) ext[g] = (__bf16)(s * (1.f / 64.f));
  else if (j < 4) ext[16 + g * 3 + (j - 1)] = (__bf16)0.f;   // zero cols 1040..1087
}

// LoRA delta -> extension cols of wq: wq_ext[o][g] = bf16(20 * dBq@dWq * 0.01)
__global__ __launch_bounds__(256) void k_delta(
    const float* __restrict__ dW0, const float* __restrict__ dB0,
    const float* __restrict__ dW1, const float* __restrict__ dB1,
    const float* __restrict__ dW2, const float* __restrict__ dB2,
    const float* __restrict__ dW3, const float* __restrict__ dB3,
    __bf16* __restrict__ wq) {
  int i = blockIdx.x * 256 + threadIdx.x;          // 65536 = 4*1024*16
  int layer = i >> 14, o = (i >> 4) & 1023, g = i & 15;
  const float* dW = (layer == 0) ? dW0 : (layer == 1) ? dW1 : (layer == 2) ? dW2 : dW3;
  const float* dB = (layer == 0) ? dB0 : (layer == 1) ? dB1 : (layer == 2) ? dB2 : dB3;
  float acc = 0.f;
#pragma unroll
  for (int r = 0; r < 32; ++r)
    acc += (0.1f * fq(dB[o * 32 + r])) * (0.1f * fq(dW[r * 16 + g]));
  __bf16* ext = wq + (size_t)((layer << 10) | o) * KEXT + 1024;
  ext[g] = (__bf16)(20.f * acc);
#pragma unroll
  for (int k = 0; k < 3; ++k) ext[16 + g * 3 + k] = (__bf16)0.f;
}

// ---------------- GEMM (prefetch dbuf + swizzle + K-ext) --------------------
// y = 0.1 * (A_ext @ W_ext^T) over K'=1088; 128x128 tile, BK=64, 4 waves.
// mode 0: z selects Q/K/V outputs (bf16; V^T written sigma-permuted in key).
// mode 1: fp32 to d_out.
__global__ __launch_bounds__(256) void k_gemm(
    const __bf16* __restrict__ A,       // [4096][1088]
    const __bf16* __restrict__ Wq,      // [4][1024][1088]
    __bf16* __restrict__ qout,          // [bh][n][64]
    __bf16* __restrict__ kout,          // [bh][n][64]
    __bf16* __restrict__ vout,          // [bh][64][n] (sigma-permuted n)
    float* __restrict__ fout,           // [4096][1024]
    int mode, int layer_base) {
  __shared__ __align__(16) __bf16 lA[2][128 * 64];
  __shared__ __align__(16) __bf16 lB[2][128 * 64];

  const int t = threadIdx.x;
  const int lane = t & 63;
  const int wv = t >> 6;
  const int bm = blockIdx.y;
  const int bn = blockIdx.x;
  const int layer = layer_base + blockIdx.z;
  const __bf16* Wl = Wq + (size_t)layer * 1024 * KEXT;
  const int wm = wv >> 1, wn = wv & 1;
  const int fr = lane & 15, fq4 = lane >> 4;

  const int tr = t >> 3;                      // row within 32-row group
  const int scol = ((t & 7) ^ (tr & 7)) * 8;  // swizzled element offset

  f32x4 acc[4][4];
#pragma unroll
  for (int mi = 0; mi < 4; ++mi)
#pragma unroll
    for (int ni = 0; ni < 4; ++ni) { f32x4 z = {0.f, 0.f, 0.f, 0.f}; acc[mi][ni] = z; }

#define STAGE(kt, buf)                                                         \
  {                                                                            \
    _Pragma("unroll") for (int i = 0; i < 4; ++i) {                            \
      int row = i * 32 + tr;                                                   \
      gld16(A + (size_t)(bm * 128 + row) * KEXT + (kt)*64 + scol,              \
            (char*)lA[buf] + (i * 256 + wv * 64) * 16);                        \
      gld16(Wl + (size_t)(bn * 128 + row) * KEXT + (kt)*64 + scol,             \
            (char*)lB[buf] + (i * 256 + wv * 64) * 16);                        \
    }                                                                          \
  }

  STAGE(0, 0);
  __syncthreads();

  int cur = 0;
  for (int kt = 0; kt < 17; ++kt) {
    if (kt + 1 < 17) STAGE(kt + 1, cur ^ 1);
#pragma unroll
    for (int kk = 0; kk < 2; ++kk) {
      bf16x8 af[4], bfr[4];
#pragma unroll
      for (int mi = 0; mi < 4; ++mi)
        af[mi] = *(const bf16x8*)&lA[cur][(wm * 64 + mi * 16 + fr) * 64 +
                                          (((kk << 2) | fq4) ^ (fr & 7)) * 8];
#pragma unroll
      for (int ni = 0; ni < 4; ++ni)
        bfr[ni] = *(const bf16x8*)&lB[cur][(wn * 64 + ni * 16 + fr) * 64 +
                                           (((kk << 2) | fq4) ^ (fr & 7)) * 8];
#pragma unroll
      for (int mi = 0; mi < 4; ++mi)
#pragma unroll
        for (int ni = 0; ni < 4; ++ni)
          acc[mi][ni] = MFMA(af[mi], bfr[ni], acc[mi][ni]);
    }
    __syncthreads();   // drains vmcnt(0): next tile staged; buf[cur] reusable
    cur ^= 1;
  }
#undef STAGE

  // q scale folds 0.1 (dequant), 1/sqrt(64), log2(e) for log2-domain softmax
  const float outmul =
      (mode == 0 && blockIdx.z == 0) ? 0.1f * 0.125f * 1.4426950408889634f : 0.1f;
#pragma unroll
  for (int mi = 0; mi < 4; ++mi)
#pragma unroll
    for (int ni = 0; ni < 4; ++ni) {
      int o = bn * 128 + wn * 64 + ni * 16 + fr;
      if (mode == 0 && blockIdx.z == 2) {
        // V^T: 4 consecutive keys -> one 8B store at sigma-permuted position.
        // sigma (within each 64-key tile): key c*8+q*4+j -> pos
        //   ((c&4)|(q<<1)|(c&1))*8 + ((c&2)<<1) + j
        int m0 = bm * 128 + wm * 64 + mi * 16 + fq4 * 4;
        int b = m0 >> 11, nr0 = m0 & 2047;
        int kt = nr0 >> 6, l0 = nr0 & 63;
        int c = l0 >> 3, q = (l0 >> 2) & 1;
        int np = (kt << 6) | (((c & 4) | (q << 1) | (c & 1)) << 3) | ((c & 2) << 1);
        int h = o >> 6, d = o & 63;
        __bf16 pk[4];
#pragma unroll
        for (int j = 0; j < 4; ++j) pk[j] = (__bf16)(acc[mi][ni][j] * outmul);
        *(uint2*)(vout + ((size_t)(b * 16 + h) * 64 + d) * 2048 + np) = *(uint2*)pk;
      } else {
#pragma unroll
        for (int j = 0; j < 4; ++j) {
          int m = bm * 128 + wm * 64 + mi * 16 + fq4 * 4 + j;
          float v = acc[mi][ni][j] * outmul;
          if (mode == 0) {
            int b = m >> 11, nr = m & 2047;
            int h = o >> 6, d = o & 63;
            if (blockIdx.z == 0)
              qout[((size_t)(b * 16 + h) * 2048 + nr) * 64 + d] = (__bf16)v;
            else
              kout[((size_t)(b * 16 + h) * 2048 + nr) * 64 + d] = (__bf16)v;
          } else {
            fout[(size_t)m * 1024 + o] = v;
          }
        }
      }
    }
}

// ---------------- flash attention (round 6: QBLK=128, b128 PV) -------------
// Swapped QK^T: s[ni][j] = S[q=fr][key=16ni+4g+j] (lane-local P rows).
// pa[kk][e] = exp2(s[2kk+(e>>2)][e&3]) feeds PV directly; the contraction-axis
// permutation is baked into vbt's sigma-permuted key layout, so the V fragment
// is ONE swizzled ds_read_b128 (same conflict-free pattern as the K read).
// Each wave handles two 16-row q-sets sharing all kf/vf LDS reads.
__global__ __launch_bounds__(256) void k_attn(
    const __bf16* __restrict__ qb,   // [bh][n][64] (pre-scaled, log2 domain)
    const __bf16* __restrict__ kb,   // [bh][n][64]
    const __bf16* __restrict__ vbt,  // [bh][64][n] (sigma-permuted n)
    __bf16* __restrict__ attnb) {    // [4096][1088] (ext cols = head means)
  __shared__ __align__(16) __bf16 lK[2][64 * 64];
  __shared__ __align__(16) __bf16 lVT[2][64 * 64];

  const int t = threadIdx.x, lane = t & 63, wv = t >> 6;
  const int bh = blockIdx.y;
  const int qt = blockIdx.x;           // 0..15 (128 q-rows per block)
  const int fr = lane & 15, g = lane >> 4;
  const int qrow0 = qt * 128 + wv * 16;
  const size_t hbase = (size_t)bh * 2048 * 64;

  const int srow0 = t >> 3, sc0 = (t & 7) ^ (srow0 & 7);
  const int srow1 = (256 + t) >> 3, sc1 = (t & 7) ^ (srow1 & 7);
  const int dst0 = (wv * 64) * 16, dst1 = (256 + wv * 64) * 16;

  bf16x8 qf[2][2];
#pragma unroll
  for (int s = 0; s < 2; ++s)
#pragma unroll
    for (int kk = 0; kk < 2; ++kk)
      qf[s][kk] = *(const bf16x8*)(qb + hbase + (size_t)(qrow0 + s * 64 + fr) * 64 +
                                   kk * 32 + g * 8);

  bf16x8 vones;
#pragma unroll
  for (int e = 0; e < 8; ++e) vones[e] = (__bf16)1.0f;

  f32x4 o[2][4], o4[2];
#pragma unroll
  for (int s = 0; s < 2; ++s) {
#pragma unroll
    for (int di = 0; di < 4; ++di) { f32x4 z = {0.f, 0.f, 0.f, 0.f}; o[s][di] = z; }
    f32x4 z = {0.f, 0.f, 0.f, 0.f};
    o4[s] = z;
  }

  gld16(kb + hbase + (size_t)(srow0)*64 + sc0 * 8, (char*)lK[0] + dst0);
  gld16(vbt + hbase + (size_t)srow0 * 2048 + sc0 * 8, (char*)lVT[0] + dst0);
  gld16(kb + hbase + (size_t)(srow1)*64 + sc1 * 8, (char*)lK[0] + dst1);
  gld16(vbt + hbase + (size_t)srow1 * 2048 + sc1 * 8, (char*)lVT[0] + dst1);
  __syncthreads();

  int cur = 0;
  for (int kt = 0; kt < 32; ++kt) {
    if (kt + 1 < 32) {
      int kn = (kt + 1) * 64;
      gld16(kb + hbase + (size_t)(kn + srow0) * 64 + sc0 * 8, (char*)lK[cur ^ 1] + dst0);
      gld16(vbt + hbase + (size_t)srow0 * 2048 + kn + sc0 * 8, (char*)lVT[cur ^ 1] + dst0);
      gld16(kb + hbase + (size_t)(kn + srow1) * 64 + sc1 * 8, (char*)lK[cur ^ 1] + dst1);
      gld16(vbt + hbase + (size_t)srow1 * 2048 + kn + sc1 * 8, (char*)lVT[cur ^ 1] + dst1);
    }

    // S^T = K Q^T for both q-sets (kf reads shared)
    f32x4 sm[2][4];
#pragma unroll
    for (int s = 0; s < 2; ++s)
#pragma unroll
      for (int ni = 0; ni < 4; ++ni) { f32x4 z = {0.f, 0.f, 0.f, 0.f}; sm[s][ni] = z; }
    __builtin_amdgcn_s_setprio(1);
#pragma unroll
    for (int kk = 0; kk < 2; ++kk)
#pragma unroll
      for (int ni = 0; ni < 4; ++ni) {
        bf16x8 kf = *(const bf16x8*)&lK[cur][(ni * 16 + fr) * 64 +
                                            (((kk << 2) | g) ^ (fr & 7)) * 8];
        sm[0][ni] = MFMA(kf, qf[0][kk], sm[0][ni]);
        sm[1][ni] = MFMA(kf, qf[1][kk], sm[1][ni]);
      }
    __builtin_amdgcn_s_setprio(0);

    // P = exp2(S) packed into MFMA A-fragments (lane-local)
    bf16x8 pa[2][2];
#pragma unroll
    for (int s = 0; s < 2; ++s)
#pragma unroll
      for (int kk = 0; kk < 2; ++kk)
#pragma unroll
        for (int e = 0; e < 8; ++e)
          pa[s][kk][e] = (__bf16)__builtin_amdgcn_exp2f(sm[s][2 * kk + (e >> 2)][e & 3]);

    // O += P V ; denominator += P @ ones (vf reads shared across q-sets)
    __builtin_amdgcn_s_setprio(1);
#pragma unroll
    for (int kk = 0; kk < 2; ++kk) {
      const int ncr = ((kk << 2) | ((g & 1) << 1) | (g >> 1)) ^ (fr & 7);
#pragma unroll
      for (int di = 0; di < 4; ++di) {
        bf16x8 vf = *(const bf16x8*)&lVT[cur][(di * 16 + fr) * 64 + ncr * 8];
        o[0][di] = MFMA(pa[0][kk], vf, o[0][di]);
        o[1][di] = MFMA(pa[1][kk], vf, o[1][di]);
      }
      o4[0] = MFMA(pa[0][kk], vones, o4[0]);
      o4[1] = MFMA(pa[1][kk], vones, o4[1]);
    }
    __builtin_amdgcn_s_setprio(0);

    __syncthreads();
    cur ^= 1;
  }

  // epilogue: normalize, write attn bf16 into stride-1088 rows + ext cols
  const int b = bh >> 4, h = bh & 15;
#pragma unroll
  for (int s = 0; s < 2; ++s)
#pragma unroll
    for (int j = 0; j < 4; ++j) {
      float inv = 1.f / o4[s][j];
      int nr = qt * 128 + s * 64 + wv * 16 + g * 4 + j;
      size_t rowbase = (size_t)(b * 2048 + nr) * KEXT;
      float rowsum = 0.f;
#pragma unroll
      for (int di = 0; di < 4; ++di) {
        float vv = o[s][di][j] * inv;
        attnb[rowbase + h * 64 + di * 16 + fr] = (__bf16)vv;
        rowsum += vv;
      }
      rowsum = redsum16(rowsum);
      if (fr == 0) attnb[rowbase + 1024 + h] = (__bf16)(rowsum * (1.f / 64.f));
      if (h < 3) attnb[rowbase + 1040 + h * 16 + fr] = (__bf16)0.f;  // zero pad
    }
}

// ---------------- launch ----------------
extern "C" void kernel_launch(void* const* d_in, const int* in_sizes, int n_in,
                              void* d_out, int out_size, void* d_ws, size_t ws_size,
                              hipStream_t stream) {
  const float* x = (const float*)d_in[0];
  const float* w_[4]  = {(const float*)d_in[1], (const float*)d_in[4],
                         (const float*)d_in[7], (const float*)d_in[10]};
  const float* dW_[4] = {(const float*)d_in[2], (const float*)d_in[5],
                         (const float*)d_in[8], (const float*)d_in[11]};
  const float* dB_[4] = {(const float*)d_in[3], (const float*)d_in[6],
                         (const float*)d_in[9], (const float*)d_in[12]};
  float* out = (float*)d_out;

  char* ws = (char*)d_ws;
  const size_t MB = 1ull << 20;
  __bf16* xbf   = (__bf16*)(ws);                 // 4096*1088*2 = 8.9 MB
  __bf16* attnb = xbf;                           // alias: xbf dead after QKV GEMM
  __bf16* wq    = (__bf16*)(ws + 9 * MB);        // 4*1024*1088*2 = 8.9 MB
  __bf16* qb    = (__bf16*)(ws + 18 * MB);       // 8 MB
  __bf16* kb    = (__bf16*)(ws + 26 * MB);       // 8 MB
  __bf16* vbt   = (__bf16*)(ws + 34 * MB);       // 8 MB -> ends 42 MB

  k_quant_w<<<4096, 256, 0, stream>>>(w_[0], w_[1], w_[2], w_[3], wq);
  k_xprep<<<4096, 256, 0, stream>>>(x, xbf);
  k_delta<<<256, 256, 0, stream>>>(dW_[0], dB_[0], dW_[1], dB_[1],
                                   dW_[2], dB_[2], dW_[3], dB_[3], wq);
  k_gemm<<<dim3(8, 32, 3), 256, 0, stream>>>(xbf, wq, qb, kb, vbt, nullptr, 0, 0);
  k_attn<<<dim3(16, 32), 256, 0, stream>>>(qb, kb, vbt, attnb);
  k_gemm<<<dim3(8, 32, 1), 256, 0, stream>>>(attnb, wq, nullptr, nullptr, nullptr,
                                             out, 1, 3);
}

// Round 7
// 140.733 us; speedup vs baseline: 1.9886x; 1.0478x over previous
//
#include <hip/hip_runtime.h>

// ---------------------------------------------------------------------------
// SelfAttention with QA-LoRA quantized projections, MI355X (gfx950)
// Round 7: T1 XCD-rectangle blockIdx swizzle on QKV-GEMM / O-GEMM / attn
//          (per-XCD working set sized to the 4MB L2), V^T epilogue repack
//          through LDS -> contiguous 16B stores. Core loops unchanged.
// ---------------------------------------------------------------------------

typedef __bf16 bf16x8 __attribute__((ext_vector_type(8)));
typedef float f32x4 __attribute__((ext_vector_type(4)));

#define MFMA(a, b, c) __builtin_amdgcn_mfma_f32_16x16x32_bf16(a, b, c, 0, 0, 0)

#define KEXT 1088   // 1024 + 64 extension cols (16 LoRA + 48 zeros)

__device__ __forceinline__ void gld16(const void* g, void* l) {
  __builtin_amdgcn_global_load_lds(
      (const __attribute__((address_space(1))) void*)g,
      (__attribute__((address_space(3))) void*)l, 16, 0, 0);
}

// fake_quantize: returns the clipped, round-half-even INTEGER (not dequantized).
__device__ __forceinline__ float fq(float v) {
  float q = rintf(v / 0.1f);           // v_rndne_f32: round half to even
  return fminf(fmaxf(q, -128.f), 127.f);
}

__device__ __forceinline__ float redsum16(float v) {
  v += __shfl_xor(v, 1);
  v += __shfl_xor(v, 2);
  v += __shfl_xor(v, 4);
  v += __shfl_xor(v, 8);
  return v;
}

// ---------------- prep kernels ----------------

// weights -> bf16 int codes into stride-1088 layout
__global__ __launch_bounds__(256) void k_quant_w(
    const float* __restrict__ w0, const float* __restrict__ w1,
    const float* __restrict__ w2, const float* __restrict__ w3,
    __bf16* __restrict__ wq) {
  int i = blockIdx.x * 256 + threadIdx.x;          // 4 * 1024 * 256
  int layer = i >> 18, rest = i & 262143;
  int o = rest >> 8, c4 = rest & 255;
  const float* src = (layer == 0) ? w0 : (layer == 1) ? w1 : (layer == 2) ? w2 : w3;
  float4 v = ((const float4*)src)[rest];
  __bf16 r[4] = {(__bf16)fq(v.x), (__bf16)fq(v.y), (__bf16)fq(v.z), (__bf16)fq(v.w)};
  *(uint2*)(wq + (size_t)((layer << 10) | o) * KEXT + (c4 << 2)) = *(uint2*)r;
}

// fused: x fp32 -> bf16 (stride 1088) AND extension cols = group means.
__global__ __launch_bounds__(256) void k_xprep(const float* __restrict__ x,
                                               __bf16* __restrict__ xbf) {
  int row = blockIdx.x, t = threadIdx.x;
  float4 v = ((const float4*)(x + (size_t)row * 1024))[t];
  __bf16 r[4] = {(__bf16)v.x, (__bf16)v.y, (__bf16)v.z, (__bf16)v.w};
  *(uint2*)(xbf + (size_t)row * KEXT + 4 * t) = *(uint2*)r;
  float s = v.x + v.y + v.z + v.w;
  s = redsum16(s);                                  // all 16 lanes of group hold sum
  int g = t >> 4, j = t & 15;
  __bf16* ext = xbf + (size_t)row * KEXT + 1024;
  if (j == 0) ext[g] = (__bf16)(s * (1.f / 64.f));
  else if (j < 4) ext[16 + g * 3 + (j - 1)] = (__bf16)0.f;   // zero cols 1040..1087
}

// LoRA delta -> extension cols of wq: wq_ext[o][g] = bf16(20 * dBq@dWq * 0.01)
__global__ __launch_bounds__(256) void k_delta(
    const float* __restrict__ dW0, const float* __restrict__ dB0,
    const float* __restrict__ dW1, const float* __restrict__ dB1,
    const float* __restrict__ dW2, const float* __restrict__ dB2,
    const float* __restrict__ dW3, const float* __restrict__ dB3,
    __bf16* __restrict__ wq) {
  int i = blockIdx.x * 256 + threadIdx.x;          // 65536 = 4*1024*16
  int layer = i >> 14, o = (i >> 4) & 1023, g = i & 15;
  const float* dW = (layer == 0) ? dW0 : (layer == 1) ? dW1 : (layer == 2) ? dW2 : dW3;
  const float* dB = (layer == 0) ? dB0 : (layer == 1) ? dB1 : (layer == 2) ? dB2 : dB3;
  float acc = 0.f;
#pragma unroll
  for (int r = 0; r < 32; ++r)
    acc += (0.1f * fq(dB[o * 32 + r])) * (0.1f * fq(dW[r * 16 + g]));
  __bf16* ext = wq + (size_t)((layer << 10) | o) * KEXT + 1024;
  ext[g] = (__bf16)(20.f * acc);
#pragma unroll
  for (int k = 0; k < 3; ++k) ext[16 + g * 3 + k] = (__bf16)0.f;
}

// ---------------- GEMM (prefetch dbuf + swizzle + K-ext + T1) ---------------
// y = 0.1 * (A_ext @ W_ext^T) over K'=1088; 128x128 tile, BK=64, 4 waves.
// mode 0: 1D grid of 768 = {bm 32} x {zn 24 = z*8+bn}; XCD rect = 8bm x 12zn.
//         z selects Q/K/V outputs; V^T repacked via LDS, sigma-permuted keys.
// mode 1: 1D grid of 256 = {bm 32} x {bn 8}; XCD rect = 8bm x 4bn; fp32 out.
__global__ __launch_bounds__(256) void k_gemm(
    const __bf16* __restrict__ A,       // [4096][1088]
    const __bf16* __restrict__ Wq,      // [4][1024][1088]
    __bf16* __restrict__ qout,          // [bh][n][64]
    __bf16* __restrict__ kout,          // [bh][n][64]
    __bf16* __restrict__ vout,          // [bh][64][n] (sigma-permuted n)
    float* __restrict__ fout,           // [4096][1024]
    int mode, int layer_base) {
  __shared__ __align__(16) __bf16 lA[2][128 * 64];
  __shared__ __align__(16) __bf16 lB[2][128 * 64];

  const int t = threadIdx.x;
  const int lane = t & 63;
  const int wv = t >> 6;

  // T1: XCD-rectangle decode (hw maps consecutive blockIdx round-robin to XCDs)
  int bm, bn, z;
  {
    int xcd = blockIdx.x & 7, local = blockIdx.x >> 3;
    if (mode == 0) {                     // 768 blocks: local 0..95 = 8bm x 12zn
      int bm_l = local / 12, zn_l = local - bm_l * 12;
      bm = ((xcd >> 1) << 3) + bm_l;
      int zn = (xcd & 1) * 12 + zn_l;
      z = zn >> 3;
      bn = zn & 7;
    } else {                             // 256 blocks: local 0..31 = 8bm x 4bn
      int bm_l = local >> 2, bn_l = local & 3;
      bm = ((xcd >> 1) << 3) + bm_l;
      bn = (xcd & 1) * 4 + bn_l;
      z = 0;
    }
  }
  const int layer = layer_base + z;
  const __bf16* Wl = Wq + (size_t)layer * 1024 * KEXT;
  const int wm = wv >> 1, wn = wv & 1;
  const int fr = lane & 15, fq4 = lane >> 4;

  const int tr = t >> 3;                      // row within 32-row group
  const int scol = ((t & 7) ^ (tr & 7)) * 8;  // swizzled element offset

  f32x4 acc[4][4];
#pragma unroll
  for (int mi = 0; mi < 4; ++mi)
#pragma unroll
    for (int ni = 0; ni < 4; ++ni) { f32x4 zz = {0.f, 0.f, 0.f, 0.f}; acc[mi][ni] = zz; }

#define STAGE(kt, buf)                                                         \
  {                                                                            \
    _Pragma("unroll") for (int i = 0; i < 4; ++i) {                            \
      int row = i * 32 + tr;                                                   \
      gld16(A + (size_t)(bm * 128 + row) * KEXT + (kt)*64 + scol,              \
            (char*)lA[buf] + (i * 256 + wv * 64) * 16);                        \
      gld16(Wl + (size_t)(bn * 128 + row) * KEXT + (kt)*64 + scol,             \
            (char*)lB[buf] + (i * 256 + wv * 64) * 16);                        \
    }                                                                          \
  }

  STAGE(0, 0);
  __syncthreads();

  int cur = 0;
  for (int kt = 0; kt < 17; ++kt) {
    if (kt + 1 < 17) STAGE(kt + 1, cur ^ 1);
#pragma unroll
    for (int kk = 0; kk < 2; ++kk) {
      bf16x8 af[4], bfr[4];
#pragma unroll
      for (int mi = 0; mi < 4; ++mi)
        af[mi] = *(const bf16x8*)&lA[cur][(wm * 64 + mi * 16 + fr) * 64 +
                                          (((kk << 2) | fq4) ^ (fr & 7)) * 8];
#pragma unroll
      for (int ni = 0; ni < 4; ++ni)
        bfr[ni] = *(const bf16x8*)&lB[cur][(wn * 64 + ni * 16 + fr) * 64 +
                                           (((kk << 2) | fq4) ^ (fr & 7)) * 8];
#pragma unroll
      for (int mi = 0; mi < 4; ++mi)
#pragma unroll
        for (int ni = 0; ni < 4; ++ni)
          acc[mi][ni] = MFMA(af[mi], bfr[ni], acc[mi][ni]);
    }
    __syncthreads();   // drains vmcnt(0): next tile staged; buf[cur] reusable
    cur ^= 1;
  }
#undef STAGE

  // q scale folds 0.1 (dequant), 1/sqrt(64), log2(e) for log2-domain softmax
  const float outmul =
      (mode == 0 && z == 0) ? 0.1f * 0.125f * 1.4426950408889634f : 0.1f;

  if (mode == 0 && z == 2) {
    // --- V^T epilogue: repack via LDS (dead after final barrier) ------------
    // Wave tile = 64 rows (n) x 64 cols (d), single head h = bn*2+wn.
    // LDS [d][sigma(n_local)] with 16B-chunk XOR swizzle; then each lane
    // stores one d-row as 8 contiguous 16B chunks (128B/row, coalesced).
    __bf16* lw = ((__bf16*)lA) + wv * 4096;   // 8KB wave-private
#pragma unroll
    for (int mi = 0; mi < 4; ++mi) {
      int cc = mi * 2 + (fq4 >> 1), qq = fq4 & 1;
      int sb = (((cc & 4) | (qq << 1) | (cc & 1)) << 3) | ((cc & 2) << 1);
      int lc = sb >> 3, half = (sb >> 2) & 1;
#pragma unroll
      for (int ni = 0; ni < 4; ++ni) {
        int d = ni * 16 + fr;
        __bf16 pk[4];
#pragma unroll
        for (int j = 0; j < 4; ++j) pk[j] = (__bf16)(acc[mi][ni][j] * outmul);
        *(uint2*)&lw[d * 64 + ((lc ^ (d & 7)) << 3) + half * 4] = *(uint2*)pk;
      }
    }
    // same-wave DS ordering: writes visible to own reads, no barrier
    int d = lane;
    int m0 = bm * 128 + wm * 64;
    int b = m0 >> 11, n0 = m0 & 2047;
    int h = bn * 2 + wn;
    __bf16* vrow = vout + ((size_t)(b * 16 + h) * 64 + d) * 2048 + n0;
#pragma unroll
    for (int lc2 = 0; lc2 < 8; ++lc2) {
      uint4 val = *(uint4*)&lw[d * 64 + ((lc2 ^ (d & 7)) << 3)];
      *(uint4*)(vrow + lc2 * 8) = val;
    }
  } else {
#pragma unroll
    for (int mi = 0; mi < 4; ++mi)
#pragma unroll
      for (int ni = 0; ni < 4; ++ni) {
        int o = bn * 128 + wn * 64 + ni * 16 + fr;
#pragma unroll
        for (int j = 0; j < 4; ++j) {
          int m = bm * 128 + wm * 64 + mi * 16 + fq4 * 4 + j;
          float v = acc[mi][ni][j] * outmul;
          if (mode == 0) {
            int b = m >> 11, nr = m & 2047;
            int h = o >> 6, d = o & 63;
            if (z == 0)
              qout[((size_t)(b * 16 + h) * 2048 + nr) * 64 + d] = (__bf16)v;
            else
              kout[((size_t)(b * 16 + h) * 2048 + nr) * 64 + d] = (__bf16)v;
          } else {
            fout[(size_t)m * 1024 + o] = v;
          }
        }
      }
  }
}

// ---------------- flash attention (round 6 structure + T1) ------------------
__global__ __launch_bounds__(256) void k_attn(
    const __bf16* __restrict__ qb,   // [bh][n][64] (pre-scaled, log2 domain)
    const __bf16* __restrict__ kb,   // [bh][n][64]
    const __bf16* __restrict__ vbt,  // [bh][64][n] (sigma-permuted n)
    __bf16* __restrict__ attnb) {    // [4096][1088] (ext cols = head means)
  __shared__ __align__(16) __bf16 lK[2][64 * 64];
  __shared__ __align__(16) __bf16 lVT[2][64 * 64];

  const int t = threadIdx.x, lane = t & 63, wv = t >> 6;
  // T1: XCD rect = 4bh x 16qt -> each bh's K/V fetched by one XCD only
  const int xcd = blockIdx.x & 7, local = blockIdx.x >> 3;   // local 0..63
  const int bh = xcd * 4 + (local >> 4);
  const int qt = local & 15;                   // 0..15 (128 q-rows per block)
  const int fr = lane & 15, g = lane >> 4;
  const int qrow0 = qt * 128 + wv * 16;
  const size_t hbase = (size_t)bh * 2048 * 64;

  const int srow0 = t >> 3, sc0 = (t & 7) ^ (srow0 & 7);
  const int srow1 = (256 + t) >> 3, sc1 = (t & 7) ^ (srow1 & 7);
  const int dst0 = (wv * 64) * 16, dst1 = (256 + wv * 64) * 16;

  bf16x8 qf[2][2];
#pragma unroll
  for (int s = 0; s < 2; ++s)
#pragma unroll
    for (int kk = 0; kk < 2; ++kk)
      qf[s][kk] = *(const bf16x8*)(qb + hbase + (size_t)(qrow0 + s * 64 + fr) * 64 +
                                   kk * 32 + g * 8);

  bf16x8 vones;
#pragma unroll
  for (int e = 0; e < 8; ++e) vones[e] = (__bf16)1.0f;

  f32x4 o[2][4], o4[2];
#pragma unroll
  for (int s = 0; s < 2; ++s) {
#pragma unroll
    for (int di = 0; di < 4; ++di) { f32x4 zz = {0.f, 0.f, 0.f, 0.f}; o[s][di] = zz; }
    f32x4 zz = {0.f, 0.f, 0.f, 0.f};
    o4[s] = zz;
  }

  gld16(kb + hbase + (size_t)(srow0)*64 + sc0 * 8, (char*)lK[0] + dst0);
  gld16(vbt + hbase + (size_t)srow0 * 2048 + sc0 * 8, (char*)lVT[0] + dst0);
  gld16(kb + hbase + (size_t)(srow1)*64 + sc1 * 8, (char*)lK[0] + dst1);
  gld16(vbt + hbase + (size_t)srow1 * 2048 + sc1 * 8, (char*)lVT[0] + dst1);
  __syncthreads();

  int cur = 0;
  for (int kt = 0; kt < 32; ++kt) {
    if (kt + 1 < 32) {
      int kn = (kt + 1) * 64;
      gld16(kb + hbase + (size_t)(kn + srow0) * 64 + sc0 * 8, (char*)lK[cur ^ 1] + dst0);
      gld16(vbt + hbase + (size_t)srow0 * 2048 + kn + sc0 * 8, (char*)lVT[cur ^ 1] + dst0);
      gld16(kb + hbase + (size_t)(kn + srow1) * 64 + sc1 * 8, (char*)lK[cur ^ 1] + dst1);
      gld16(vbt + hbase + (size_t)srow1 * 2048 + kn + sc1 * 8, (char*)lVT[cur ^ 1] + dst1);
    }

    // S^T = K Q^T for both q-sets (kf reads shared)
    f32x4 sm[2][4];
#pragma unroll
    for (int s = 0; s < 2; ++s)
#pragma unroll
      for (int ni = 0; ni < 4; ++ni) { f32x4 zz = {0.f, 0.f, 0.f, 0.f}; sm[s][ni] = zz; }
    __builtin_amdgcn_s_setprio(1);
#pragma unroll
    for (int kk = 0; kk < 2; ++kk)
#pragma unroll
      for (int ni = 0; ni < 4; ++ni) {
        bf16x8 kf = *(const bf16x8*)&lK[cur][(ni * 16 + fr) * 64 +
                                            (((kk << 2) | g) ^ (fr & 7)) * 8];
        sm[0][ni] = MFMA(kf, qf[0][kk], sm[0][ni]);
        sm[1][ni] = MFMA(kf, qf[1][kk], sm[1][ni]);
      }
    __builtin_amdgcn_s_setprio(0);

    // P = exp2(S) packed into MFMA A-fragments (lane-local)
    bf16x8 pa[2][2];
#pragma unroll
    for (int s = 0; s < 2; ++s)
#pragma unroll
      for (int kk = 0; kk < 2; ++kk)
#pragma unroll
        for (int e = 0; e < 8; ++e)
          pa[s][kk][e] = (__bf16)__builtin_amdgcn_exp2f(sm[s][2 * kk + (e >> 2)][e & 3]);

    // O += P V ; denominator += P @ ones (vf reads shared across q-sets)
    __builtin_amdgcn_s_setprio(1);
#pragma unroll
    for (int kk = 0; kk < 2; ++kk) {
      const int ncr = ((kk << 2) | ((g & 1) << 1) | (g >> 1)) ^ (fr & 7);
#pragma unroll
      for (int di = 0; di < 4; ++di) {
        bf16x8 vf = *(const bf16x8*)&lVT[cur][(di * 16 + fr) * 64 + ncr * 8];
        o[0][di] = MFMA(pa[0][kk], vf, o[0][di]);
        o[1][di] = MFMA(pa[1][kk], vf, o[1][di]);
      }
      o4[0] = MFMA(pa[0][kk], vones, o4[0]);
      o4[1] = MFMA(pa[1][kk], vones, o4[1]);
    }
    __builtin_amdgcn_s_setprio(0);

    __syncthreads();
    cur ^= 1;
  }

  // epilogue: normalize, write attn bf16 into stride-1088 rows + ext cols
  const int b = bh >> 4, h = bh & 15;
#pragma unroll
  for (int s = 0; s < 2; ++s)
#pragma unroll
    for (int j = 0; j < 4; ++j) {
      float inv = 1.f / o4[s][j];
      int nr = qt * 128 + s * 64 + wv * 16 + g * 4 + j;
      size_t rowbase = (size_t)(b * 2048 + nr) * KEXT;
      float rowsum = 0.f;
#pragma unroll
      for (int di = 0; di < 4; ++di) {
        float vv = o[s][di][j] * inv;
        attnb[rowbase + h * 64 + di * 16 + fr] = (__bf16)vv;
        rowsum += vv;
      }
      rowsum = redsum16(rowsum);
      if (fr == 0) attnb[rowbase + 1024 + h] = (__bf16)(rowsum * (1.f / 64.f));
      if (h < 3) attnb[rowbase + 1040 + h * 16 + fr] = (__bf16)0.f;  // zero pad
    }
}

// ---------------- launch ----------------
extern "C" void kernel_launch(void* const* d_in, const int* in_sizes, int n_in,
                              void* d_out, int out_size, void* d_ws, size_t ws_size,
                              hipStream_t stream) {
  const float* x = (const float*)d_in[0];
  const float* w_[4]  = {(const float*)d_in[1], (const float*)d_in[4],
                         (const float*)d_in[7], (const float*)d_in[10]};
  const float* dW_[4] = {(const float*)d_in[2], (const float*)d_in[5],
                         (const float*)d_in[8], (const float*)d_in[11]};
  const float* dB_[4] = {(const float*)d_in[3], (const float*)d_in[6],
                         (const float*)d_in[9], (const float*)d_in[12]};
  float* out = (float*)d_out;

  char* ws = (char*)d_ws;
  const size_t MB = 1ull << 20;
  __bf16* xbf   = (__bf16*)(ws);                 // 4096*1088*2 = 8.9 MB
  __bf16* attnb = xbf;                           // alias: xbf dead after QKV GEMM
  __bf16* wq    = (__bf16*)(ws + 9 * MB);        // 4*1024*1088*2 = 8.9 MB
  __bf16* qb    = (__bf16*)(ws + 18 * MB);       // 8 MB
  __bf16* kb    = (__bf16*)(ws + 26 * MB);       // 8 MB
  __bf16* vbt   = (__bf16*)(ws + 34 * MB);       // 8 MB -> ends 42 MB

  k_quant_w<<<4096, 256, 0, stream>>>(w_[0], w_[1], w_[2], w_[3], wq);
  k_xprep<<<4096, 256, 0, stream>>>(x, xbf);
  k_delta<<<256, 256, 0, stream>>>(dW_[0], dB_[0], dW_[1], dB_[1],
                                   dW_[2], dB_[2], dW_[3], dB_[3], wq);
  k_gemm<<<768, 256, 0, stream>>>(xbf, wq, qb, kb, vbt, nullptr, 0, 0);
  k_attn<<<512, 256, 0, stream>>>(qb, kb, vbt, attnb);
  k_gemm<<<256, 256, 0, stream>>>(attnb, wq, nullptr, nullptr, nullptr,
                                  out, 1, 3);
}

// Round 8
// 131.748 us; speedup vs baseline: 2.1243x; 1.0682x over previous
//
#include <hip/hip_runtime.h>

// ---------------------------------------------------------------------------
// SelfAttention with QA-LoRA quantized projections, MI355X (gfx950)
// Round 8: attn att[2]-style software pipeline — QK^T(t) MFMAs interleave
//          with exp+PV(t-1) (trans/VALU), V double-buffer phase-shifted by
//          one tile. Named smA/smB ping-pong via 2x-unrolled loop (rule #20).
//          GEMMs / prep / T1 swizzles unchanged from round 7.
// ---------------------------------------------------------------------------

typedef __bf16 bf16x8 __attribute__((ext_vector_type(8)));
typedef float f32x4 __attribute__((ext_vector_type(4)));

#define MFMA(a, b, c) __builtin_amdgcn_mfma_f32_16x16x32_bf16(a, b, c, 0, 0, 0)

#define KEXT 1088   // 1024 + 64 extension cols (16 LoRA + 48 zeros)

__device__ __forceinline__ void gld16(const void* g, void* l) {
  __builtin_amdgcn_global_load_lds(
      (const __attribute__((address_space(1))) void*)g,
      (__attribute__((address_space(3))) void*)l, 16, 0, 0);
}

// fake_quantize: returns the clipped, round-half-even INTEGER (not dequantized).
__device__ __forceinline__ float fq(float v) {
  float q = rintf(v / 0.1f);           // v_rndne_f32: round half to even
  return fminf(fmaxf(q, -128.f), 127.f);
}

__device__ __forceinline__ float redsum16(float v) {
  v += __shfl_xor(v, 1);
  v += __shfl_xor(v, 2);
  v += __shfl_xor(v, 4);
  v += __shfl_xor(v, 8);
  return v;
}

// ---------------- prep kernels ----------------

// weights -> bf16 int codes into stride-1088 layout
__global__ __launch_bounds__(256) void k_quant_w(
    const float* __restrict__ w0, const float* __restrict__ w1,
    const float* __restrict__ w2, const float* __restrict__ w3,
    __bf16* __restrict__ wq) {
  int i = blockIdx.x * 256 + threadIdx.x;          // 4 * 1024 * 256
  int layer = i >> 18, rest = i & 262143;
  int o = rest >> 8, c4 = rest & 255;
  const float* src = (layer == 0) ? w0 : (layer == 1) ? w1 : (layer == 2) ? w2 : w3;
  float4 v = ((const float4*)src)[rest];
  __bf16 r[4] = {(__bf16)fq(v.x), (__bf16)fq(v.y), (__bf16)fq(v.z), (__bf16)fq(v.w)};
  *(uint2*)(wq + (size_t)((layer << 10) | o) * KEXT + (c4 << 2)) = *(uint2*)r;
}

// fused: x fp32 -> bf16 (stride 1088) AND extension cols = group means.
__global__ __launch_bounds__(256) void k_xprep(const float* __restrict__ x,
                                               __bf16* __restrict__ xbf) {
  int row = blockIdx.x, t = threadIdx.x;
  float4 v = ((const float4*)(x + (size_t)row * 1024))[t];
  __bf16 r[4] = {(__bf16)v.x, (__bf16)v.y, (__bf16)v.z, (__bf16)v.w};
  *(uint2*)(xbf + (size_t)row * KEXT + 4 * t) = *(uint2*)r;
  float s = v.x + v.y + v.z + v.w;
  s = redsum16(s);                                  // all 16 lanes of group hold sum
  int g = t >> 4, j = t & 15;
  __bf16* ext = xbf + (size_t)row * KEXT + 1024;
  if (j == 0) ext[g] = (__bf16)(s * (1.f / 64.f));
  else if (j < 4) ext[16 + g * 3 + (j - 1)] = (__bf16)0.f;   // zero cols 1040..1087
}

// LoRA delta -> extension cols of wq: wq_ext[o][g] = bf16(20 * dBq@dWq * 0.01)
__global__ __launch_bounds__(256) void k_delta(
    const float* __restrict__ dW0, const float* __restrict__ dB0,
    const float* __restrict__ dW1, const float* __restrict__ dB1,
    const float* __restrict__ dW2, const float* __restrict__ dB2,
    const float* __restrict__ dW3, const float* __restrict__ dB3,
    __bf16* __restrict__ wq) {
  int i = blockIdx.x * 256 + threadIdx.x;          // 65536 = 4*1024*16
  int layer = i >> 14, o = (i >> 4) & 1023, g = i & 15;
  const float* dW = (layer == 0) ? dW0 : (layer == 1) ? dW1 : (layer == 2) ? dW2 : dW3;
  const float* dB = (layer == 0) ? dB0 : (layer == 1) ? dB1 : (layer == 2) ? dB2 : dB3;
  float acc = 0.f;
#pragma unroll
  for (int r = 0; r < 32; ++r)
    acc += (0.1f * fq(dB[o * 32 + r])) * (0.1f * fq(dW[r * 16 + g]));
  __bf16* ext = wq + (size_t)((layer << 10) | o) * KEXT + 1024;
  ext[g] = (__bf16)(20.f * acc);
#pragma unroll
  for (int k = 0; k < 3; ++k) ext[16 + g * 3 + k] = (__bf16)0.f;
}

// ---------------- GEMM (prefetch dbuf + swizzle + K-ext + T1) ---------------
// y = 0.1 * (A_ext @ W_ext^T) over K'=1088; 128x128 tile, BK=64, 4 waves.
// mode 0: 1D grid of 768 = {bm 32} x {zn 24 = z*8+bn}; XCD rect = 8bm x 12zn.
//         z selects Q/K/V outputs; V^T repacked via LDS, sigma-permuted keys.
// mode 1: 1D grid of 256 = {bm 32} x {bn 8}; XCD rect = 8bm x 4bn; fp32 out.
__global__ __launch_bounds__(256) void k_gemm(
    const __bf16* __restrict__ A,       // [4096][1088]
    const __bf16* __restrict__ Wq,      // [4][1024][1088]
    __bf16* __restrict__ qout,          // [bh][n][64]
    __bf16* __restrict__ kout,          // [bh][n][64]
    __bf16* __restrict__ vout,          // [bh][64][n] (sigma-permuted n)
    float* __restrict__ fout,           // [4096][1024]
    int mode, int layer_base) {
  __shared__ __align__(16) __bf16 lA[2][128 * 64];
  __shared__ __align__(16) __bf16 lB[2][128 * 64];

  const int t = threadIdx.x;
  const int lane = t & 63;
  const int wv = t >> 6;

  // T1: XCD-rectangle decode (hw maps consecutive blockIdx round-robin to XCDs)
  int bm, bn, z;
  {
    int xcd = blockIdx.x & 7, local = blockIdx.x >> 3;
    if (mode == 0) {                     // 768 blocks: local 0..95 = 8bm x 12zn
      int bm_l = local / 12, zn_l = local - bm_l * 12;
      bm = ((xcd >> 1) << 3) + bm_l;
      int zn = (xcd & 1) * 12 + zn_l;
      z = zn >> 3;
      bn = zn & 7;
    } else {                             // 256 blocks: local 0..31 = 8bm x 4bn
      int bm_l = local >> 2, bn_l = local & 3;
      bm = ((xcd >> 1) << 3) + bm_l;
      bn = (xcd & 1) * 4 + bn_l;
      z = 0;
    }
  }
  const int layer = layer_base + z;
  const __bf16* Wl = Wq + (size_t)layer * 1024 * KEXT;
  const int wm = wv >> 1, wn = wv & 1;
  const int fr = lane & 15, fq4 = lane >> 4;

  const int tr = t >> 3;                      // row within 32-row group
  const int scol = ((t & 7) ^ (tr & 7)) * 8;  // swizzled element offset

  f32x4 acc[4][4];
#pragma unroll
  for (int mi = 0; mi < 4; ++mi)
#pragma unroll
    for (int ni = 0; ni < 4; ++ni) { f32x4 zz = {0.f, 0.f, 0.f, 0.f}; acc[mi][ni] = zz; }

#define STAGE(kt, buf)                                                         \
  {                                                                            \
    _Pragma("unroll") for (int i = 0; i < 4; ++i) {                            \
      int row = i * 32 + tr;                                                   \
      gld16(A + (size_t)(bm * 128 + row) * KEXT + (kt)*64 + scol,              \
            (char*)lA[buf] + (i * 256 + wv * 64) * 16);                        \
      gld16(Wl + (size_t)(bn * 128 + row) * KEXT + (kt)*64 + scol,             \
            (char*)lB[buf] + (i * 256 + wv * 64) * 16);                        \
    }                                                                          \
  }

  STAGE(0, 0);
  __syncthreads();

  int cur = 0;
  for (int kt = 0; kt < 17; ++kt) {
    if (kt + 1 < 17) STAGE(kt + 1, cur ^ 1);
#pragma unroll
    for (int kk = 0; kk < 2; ++kk) {
      bf16x8 af[4], bfr[4];
#pragma unroll
      for (int mi = 0; mi < 4; ++mi)
        af[mi] = *(const bf16x8*)&lA[cur][(wm * 64 + mi * 16 + fr) * 64 +
                                          (((kk << 2) | fq4) ^ (fr & 7)) * 8];
#pragma unroll
      for (int ni = 0; ni < 4; ++ni)
        bfr[ni] = *(const bf16x8*)&lB[cur][(wn * 64 + ni * 16 + fr) * 64 +
                                           (((kk << 2) | fq4) ^ (fr & 7)) * 8];
#pragma unroll
      for (int mi = 0; mi < 4; ++mi)
#pragma unroll
        for (int ni = 0; ni < 4; ++ni)
          acc[mi][ni] = MFMA(af[mi], bfr[ni], acc[mi][ni]);
    }
    __syncthreads();   // drains vmcnt(0): next tile staged; buf[cur] reusable
    cur ^= 1;
  }
#undef STAGE

  // q scale folds 0.1 (dequant), 1/sqrt(64), log2(e) for log2-domain softmax
  const float outmul =
      (mode == 0 && z == 0) ? 0.1f * 0.125f * 1.4426950408889634f : 0.1f;

  if (mode == 0 && z == 2) {
    // --- V^T epilogue: repack via LDS (dead after final barrier) ------------
    __bf16* lw = ((__bf16*)lA) + wv * 4096;   // 8KB wave-private
#pragma unroll
    for (int mi = 0; mi < 4; ++mi) {
      int cc = mi * 2 + (fq4 >> 1), qq = fq4 & 1;
      int sb = (((cc & 4) | (qq << 1) | (cc & 1)) << 3) | ((cc & 2) << 1);
      int lc = sb >> 3, half = (sb >> 2) & 1;
#pragma unroll
      for (int ni = 0; ni < 4; ++ni) {
        int d = ni * 16 + fr;
        __bf16 pk[4];
#pragma unroll
        for (int j = 0; j < 4; ++j) pk[j] = (__bf16)(acc[mi][ni][j] * outmul);
        *(uint2*)&lw[d * 64 + ((lc ^ (d & 7)) << 3) + half * 4] = *(uint2*)pk;
      }
    }
    // same-wave DS ordering: writes visible to own reads, no barrier
    int d = lane;
    int m0 = bm * 128 + wm * 64;
    int b = m0 >> 11, n0 = m0 & 2047;
    int h = bn * 2 + wn;
    __bf16* vrow = vout + ((size_t)(b * 16 + h) * 64 + d) * 2048 + n0;
#pragma unroll
    for (int lc2 = 0; lc2 < 8; ++lc2) {
      uint4 val = *(uint4*)&lw[d * 64 + ((lc2 ^ (d & 7)) << 3)];
      *(uint4*)(vrow + lc2 * 8) = val;
    }
  } else {
#pragma unroll
    for (int mi = 0; mi < 4; ++mi)
#pragma unroll
      for (int ni = 0; ni < 4; ++ni) {
        int o = bn * 128 + wn * 64 + ni * 16 + fr;
#pragma unroll
        for (int j = 0; j < 4; ++j) {
          int m = bm * 128 + wm * 64 + mi * 16 + fq4 * 4 + j;
          float v = acc[mi][ni][j] * outmul;
          if (mode == 0) {
            int b = m >> 11, nr = m & 2047;
            int h = o >> 6, d = o & 63;
            if (z == 0)
              qout[((size_t)(b * 16 + h) * 2048 + nr) * 64 + d] = (__bf16)v;
            else
              kout[((size_t)(b * 16 + h) * 2048 + nr) * 64 + d] = (__bf16)v;
          } else {
            fout[(size_t)m * 1024 + o] = v;
          }
        }
      }
  }
}

// ---------------- flash attention (round 8: QK(t) || exp/PV(t-1)) ----------
__global__ __launch_bounds__(256) void k_attn(
    const __bf16* __restrict__ qb,   // [bh][n][64] (pre-scaled, log2 domain)
    const __bf16* __restrict__ kb,   // [bh][n][64]
    const __bf16* __restrict__ vbt,  // [bh][64][n] (sigma-permuted n)
    __bf16* __restrict__ attnb) {    // [4096][1088] (ext cols = head means)
  __shared__ __align__(16) __bf16 lK[2][64 * 64];
  __shared__ __align__(16) __bf16 lVT[2][64 * 64];

  const int t = threadIdx.x, lane = t & 63, wv = t >> 6;
  // T1: XCD rect = 4bh x 16qt -> each bh's K/V fetched by one XCD only
  const int xcd = blockIdx.x & 7, local = blockIdx.x >> 3;   // local 0..63
  const int bh = xcd * 4 + (local >> 4);
  const int qt = local & 15;                   // 0..15 (128 q-rows per block)
  const int fr = lane & 15, g = lane >> 4;
  const int qrow0 = qt * 128 + wv * 16;
  const size_t hbase = (size_t)bh * 2048 * 64;

  const int srow0 = t >> 3, sc0 = (t & 7) ^ (srow0 & 7);
  const int srow1 = (256 + t) >> 3, sc1 = (t & 7) ^ (srow1 & 7);
  const int dst0 = (wv * 64) * 16, dst1 = (256 + wv * 64) * 16;

  bf16x8 qf[2][2];
#pragma unroll
  for (int s = 0; s < 2; ++s)
#pragma unroll
    for (int kk = 0; kk < 2; ++kk)
      qf[s][kk] = *(const bf16x8*)(qb + hbase + (size_t)(qrow0 + s * 64 + fr) * 64 +
                                   kk * 32 + g * 8);

  bf16x8 vones;
#pragma unroll
  for (int e = 0; e < 8; ++e) vones[e] = (__bf16)1.0f;

  f32x4 o[2][4], o4[2];
#pragma unroll
  for (int s = 0; s < 2; ++s) {
#pragma unroll
    for (int di = 0; di < 4; ++di) { f32x4 zz = {0.f, 0.f, 0.f, 0.f}; o[s][di] = zz; }
    f32x4 zz = {0.f, 0.f, 0.f, 0.f};
    o4[s] = zz;
  }

  f32x4 smA[2][4], smB[2][4];

// stage K/V tile KT into BUF (2 gld16 each; sources pre-swizzled, rule #21)
#define SK_STAGE(KT, BUF)                                                      \
  {                                                                            \
    int kn = (KT)*64;                                                          \
    gld16(kb + hbase + (size_t)(kn + srow0) * 64 + sc0 * 8, (char*)(BUF) + dst0); \
    gld16(kb + hbase + (size_t)(kn + srow1) * 64 + sc1 * 8, (char*)(BUF) + dst1); \
  }
#define SV_STAGE(KT, BUF)                                                      \
  {                                                                            \
    int kn = (KT)*64;                                                          \
    gld16(vbt + hbase + (size_t)srow0 * 2048 + kn + sc0 * 8, (char*)(BUF) + dst0); \
    gld16(vbt + hbase + (size_t)srow1 * 2048 + kn + sc1 * 8, (char*)(BUF) + dst1); \
  }
// QK^T of one tile from KBUF into SM (both q-sets; kf reads shared)
#define QK_STEP(KBUF, SM)                                                      \
  {                                                                            \
    _Pragma("unroll") for (int ni = 0; ni < 4; ++ni) {                         \
      f32x4 zz = {0.f, 0.f, 0.f, 0.f};                                         \
      SM[0][ni] = zz;                                                          \
      SM[1][ni] = zz;                                                          \
    }                                                                          \
    _Pragma("unroll") for (int kk = 0; kk < 2; ++kk)                           \
        _Pragma("unroll") for (int ni = 0; ni < 4; ++ni) {                     \
      bf16x8 kf = *(const bf16x8*)&(KBUF)[(ni * 16 + fr) * 64 +                \
                                          (((kk << 2) | g) ^ (fr & 7)) * 8];   \
      SM[0][ni] = MFMA(kf, qf[0][kk], SM[0][ni]);                              \
      SM[1][ni] = MFMA(kf, qf[1][kk], SM[1][ni]);                              \
    }                                                                          \
  }
// exp2 of SM -> pa fragments, then PV + ones-column from VBUF
#define EXPPV_STEP(SM, VBUF)                                                   \
  {                                                                            \
    bf16x8 pa[2][2];                                                           \
    _Pragma("unroll") for (int s2 = 0; s2 < 2; ++s2)                           \
        _Pragma("unroll") for (int kk = 0; kk < 2; ++kk)                       \
            _Pragma("unroll") for (int e = 0; e < 8; ++e)                      \
                pa[s2][kk][e] = (__bf16)__builtin_amdgcn_exp2f(                \
                    SM[s2][2 * kk + (e >> 2)][e & 3]);                         \
    _Pragma("unroll") for (int kk = 0; kk < 2; ++kk) {                         \
      const int ncr = ((kk << 2) | ((g & 1) << 1) | (g >> 1)) ^ (fr & 7);      \
      _Pragma("unroll") for (int di = 0; di < 4; ++di) {                       \
        bf16x8 vf = *(const bf16x8*)&(VBUF)[(di * 16 + fr) * 64 + ncr * 8];    \
        o[0][di] = MFMA(pa[0][kk], vf, o[0][di]);                              \
        o[1][di] = MFMA(pa[1][kk], vf, o[1][di]);                              \
      }                                                                        \
      o4[0] = MFMA(pa[0][kk], vones, o4[0]);                                   \
      o4[1] = MFMA(pa[1][kk], vones, o4[1]);                                   \
    }                                                                          \
  }

  // prologue: K(0) staged
  SK_STAGE(0, lK[0]);
  __syncthreads();

  // Pipeline invariants at even iter t (cur=0): lK[0]=K(t), lVT[1]=V(t-1),
  // smA=S(t-1). Stage K(t+1)->lK[1], V(t)->lVT[0] (neither read this iter);
  // QK(t)->smB overlaps exp/PV(t-1). Odd iter mirrors with buffers flipped.
  for (int it = 0; it < 16; ++it) {
    int t2 = it * 2;
    // ---- even tile t2 (cur = 0) ----
    if (t2 + 1 < 32) SK_STAGE(t2 + 1, lK[1]);
    SV_STAGE(t2, lVT[0]);
    __builtin_amdgcn_s_setprio(1);
    QK_STEP(lK[0], smB);
    if (it > 0) { EXPPV_STEP(smA, lVT[1]); }
    __builtin_amdgcn_s_setprio(0);
    __syncthreads();
    // ---- odd tile t2+1 (cur = 1) ----
    if (t2 + 2 < 32) SK_STAGE(t2 + 2, lK[0]);
    SV_STAGE(t2 + 1, lVT[1]);
    __builtin_amdgcn_s_setprio(1);
    QK_STEP(lK[1], smA);
    EXPPV_STEP(smB, lVT[0]);
    __builtin_amdgcn_s_setprio(0);
    __syncthreads();
  }
  // epilogue: tile 31 softmax+PV (V(31) in lVT[1], drained by last barrier)
  EXPPV_STEP(smA, lVT[1]);

#undef SK_STAGE
#undef SV_STAGE
#undef QK_STEP
#undef EXPPV_STEP

  // epilogue: normalize, write attn bf16 into stride-1088 rows + ext cols
  const int b = bh >> 4, h = bh & 15;
#pragma unroll
  for (int s = 0; s < 2; ++s)
#pragma unroll
    for (int j = 0; j < 4; ++j) {
      float inv = 1.f / o4[s][j];
      int nr = qt * 128 + s * 64 + wv * 16 + g * 4 + j;
      size_t rowbase = (size_t)(b * 2048 + nr) * KEXT;
      float rowsum = 0.f;
#pragma unroll
      for (int di = 0; di < 4; ++di) {
        float vv = o[s][di][j] * inv;
        attnb[rowbase + h * 64 + di * 16 + fr] = (__bf16)vv;
        rowsum += vv;
      }
      rowsum = redsum16(rowsum);
      if (fr == 0) attnb[rowbase + 1024 + h] = (__bf16)(rowsum * (1.f / 64.f));
      if (h < 3) attnb[rowbase + 1040 + h * 16 + fr] = (__bf16)0.f;  // zero pad
    }
}

// ---------------- launch ----------------
extern "C" void kernel_launch(void* const* d_in, const int* in_sizes, int n_in,
                              void* d_out, int out_size, void* d_ws, size_t ws_size,
                              hipStream_t stream) {
  const float* x = (const float*)d_in[0];
  const float* w_[4]  = {(const float*)d_in[1], (const float*)d_in[4],
                         (const float*)d_in[7], (const float*)d_in[10]};
  const float* dW_[4] = {(const float*)d_in[2], (const float*)d_in[5],
                         (const float*)d_in[8], (const float*)d_in[11]};
  const float* dB_[4] = {(const float*)d_in[3], (const float*)d_in[6],
                         (const float*)d_in[9], (const float*)d_in[12]};
  float* out = (float*)d_out;

  char* ws = (char*)d_ws;
  const size_t MB = 1ull << 20;
  __bf16* xbf   = (__bf16*)(ws);                 // 4096*1088*2 = 8.9 MB
  __bf16* attnb = xbf;                           // alias: xbf dead after QKV GEMM
  __bf16* wq    = (__bf16*)(ws + 9 * MB);        // 4*1024*1088*2 = 8.9 MB
  __bf16* qb    = (__bf16*)(ws + 18 * MB);       // 8 MB
  __bf16* kb    = (__bf16*)(ws + 26 * MB);       // 8 MB
  __bf16* vbt   = (__bf16*)(ws + 34 * MB);       // 8 MB -> ends 42 MB

  k_quant_w<<<4096, 256, 0, stream>>>(w_[0], w_[1], w_[2], w_[3], wq);
  k_xprep<<<4096, 256, 0, stream>>>(x, xbf);
  k_delta<<<256, 256, 0, stream>>>(dW_[0], dB_[0], dW_[1], dB_[1],
                                   dW_[2], dB_[2], dW_[3], dB_[3], wq);
  k_gemm<<<768, 256, 0, stream>>>(xbf, wq, qb, kb, vbt, nullptr, 0, 0);
  k_attn<<<512, 256, 0, stream>>>(qb, kb, vbt, attnb);
  k_gemm<<<256, 256, 0, stream>>>(attnb, wq, nullptr, nullptr, nullptr,
                                  out, 1, 3);
}

// Round 9
// 126.875 us; speedup vs baseline: 2.2058x; 1.0384x over previous
//
#include <hip/hip_runtime.h>

// ---------------------------------------------------------------------------
// SelfAttention with QA-LoRA quantized projections, MI355X (gfx950)
// Round 9: counted-vmcnt schedules (T4) — raw s_barrier pairs with
//          s_waitcnt vmcnt(N>0) so prefetch loads stay in flight across
//          barriers (GEMM K-loop and attn even/odd halves). Tails peeled
//          with exact immediates. Everything else unchanged from round 8.
// ---------------------------------------------------------------------------

typedef __bf16 bf16x8 __attribute__((ext_vector_type(8)));
typedef float f32x4 __attribute__((ext_vector_type(4)));

#define MFMA(a, b, c) __builtin_amdgcn_mfma_f32_16x16x32_bf16(a, b, c, 0, 0, 0)

#define KEXT 1088   // 1024 + 64 extension cols (16 LoRA + 48 zeros)

__device__ __forceinline__ void gld16(const void* g, void* l) {
  __builtin_amdgcn_global_load_lds(
      (const __attribute__((address_space(1))) void*)g,
      (__attribute__((address_space(3))) void*)l, 16, 0, 0);
}

// fake_quantize: returns the clipped, round-half-even INTEGER (not dequantized).
__device__ __forceinline__ float fq(float v) {
  float q = rintf(v / 0.1f);           // v_rndne_f32: round half to even
  return fminf(fmaxf(q, -128.f), 127.f);
}

__device__ __forceinline__ float redsum16(float v) {
  v += __shfl_xor(v, 1);
  v += __shfl_xor(v, 2);
  v += __shfl_xor(v, 4);
  v += __shfl_xor(v, 8);
  return v;
}

// ---------------- prep kernels ----------------

// weights -> bf16 int codes into stride-1088 layout
__global__ __launch_bounds__(256) void k_quant_w(
    const float* __restrict__ w0, const float* __restrict__ w1,
    const float* __restrict__ w2, const float* __restrict__ w3,
    __bf16* __restrict__ wq) {
  int i = blockIdx.x * 256 + threadIdx.x;          // 4 * 1024 * 256
  int layer = i >> 18, rest = i & 262143;
  int o = rest >> 8, c4 = rest & 255;
  const float* src = (layer == 0) ? w0 : (layer == 1) ? w1 : (layer == 2) ? w2 : w3;
  float4 v = ((const float4*)src)[rest];
  __bf16 r[4] = {(__bf16)fq(v.x), (__bf16)fq(v.y), (__bf16)fq(v.z), (__bf16)fq(v.w)};
  *(uint2*)(wq + (size_t)((layer << 10) | o) * KEXT + (c4 << 2)) = *(uint2*)r;
}

// fused: x fp32 -> bf16 (stride 1088) AND extension cols = group means.
__global__ __launch_bounds__(256) void k_xprep(const float* __restrict__ x,
                                               __bf16* __restrict__ xbf) {
  int row = blockIdx.x, t = threadIdx.x;
  float4 v = ((const float4*)(x + (size_t)row * 1024))[t];
  __bf16 r[4] = {(__bf16)v.x, (__bf16)v.y, (__bf16)v.z, (__bf16)v.w};
  *(uint2*)(xbf + (size_t)row * KEXT + 4 * t) = *(uint2*)r;
  float s = v.x + v.y + v.z + v.w;
  s = redsum16(s);                                  // all 16 lanes of group hold sum
  int g = t >> 4, j = t & 15;
  __bf16* ext = xbf + (size_t)row * KEXT + 1024;
  if (j == 0) ext[g] = (__bf16)(s * (1.f / 64.f));
  else if (j < 4) ext[16 + g * 3 + (j - 1)] = (__bf16)0.f;   // zero cols 1040..1087
}

// LoRA delta -> extension cols of wq: wq_ext[o][g] = bf16(20 * dBq@dWq * 0.01)
__global__ __launch_bounds__(256) void k_delta(
    const float* __restrict__ dW0, const float* __restrict__ dB0,
    const float* __restrict__ dW1, const float* __restrict__ dB1,
    const float* __restrict__ dW2, const float* __restrict__ dB2,
    const float* __restrict__ dW3, const float* __restrict__ dB3,
    __bf16* __restrict__ wq) {
  int i = blockIdx.x * 256 + threadIdx.x;          // 65536 = 4*1024*16
  int layer = i >> 14, o = (i >> 4) & 1023, g = i & 15;
  const float* dW = (layer == 0) ? dW0 : (layer == 1) ? dW1 : (layer == 2) ? dW2 : dW3;
  const float* dB = (layer == 0) ? dB0 : (layer == 1) ? dB1 : (layer == 2) ? dB2 : dB3;
  float acc = 0.f;
#pragma unroll
  for (int r = 0; r < 32; ++r)
    acc += (0.1f * fq(dB[o * 32 + r])) * (0.1f * fq(dW[r * 16 + g]));
  __bf16* ext = wq + (size_t)((layer << 10) | o) * KEXT + 1024;
  ext[g] = (__bf16)(20.f * acc);
#pragma unroll
  for (int k = 0; k < 3; ++k) ext[16 + g * 3 + k] = (__bf16)0.f;
}

// ---------------- GEMM (counted-vmcnt dbuf + swizzle + K-ext + T1) ----------
// y = 0.1 * (A_ext @ W_ext^T) over K'=1088; 128x128 tile, BK=64, 4 waves.
// mode 0: 1D grid of 768 = {bm 32} x {zn 24 = z*8+bn}; XCD rect = 8bm x 12zn.
// mode 1: 1D grid of 256 = {bm 32} x {bn 8}; XCD rect = 8bm x 4bn; fp32 out.
__global__ __launch_bounds__(256) void k_gemm(
    const __bf16* __restrict__ A,       // [4096][1088]
    const __bf16* __restrict__ Wq,      // [4][1024][1088]
    __bf16* __restrict__ qout,          // [bh][n][64]
    __bf16* __restrict__ kout,          // [bh][n][64]
    __bf16* __restrict__ vout,          // [bh][64][n] (sigma-permuted n)
    float* __restrict__ fout,           // [4096][1024]
    int mode, int layer_base) {
  __shared__ __align__(16) __bf16 lA[2][128 * 64];
  __shared__ __align__(16) __bf16 lB[2][128 * 64];

  const int t = threadIdx.x;
  const int lane = t & 63;
  const int wv = t >> 6;

  // T1: XCD-rectangle decode
  int bm, bn, z;
  {
    int xcd = blockIdx.x & 7, local = blockIdx.x >> 3;
    if (mode == 0) {                     // 768 blocks: local 0..95 = 8bm x 12zn
      int bm_l = local / 12, zn_l = local - bm_l * 12;
      bm = ((xcd >> 1) << 3) + bm_l;
      int zn = (xcd & 1) * 12 + zn_l;
      z = zn >> 3;
      bn = zn & 7;
    } else {                             // 256 blocks: local 0..31 = 8bm x 4bn
      int bm_l = local >> 2, bn_l = local & 3;
      bm = ((xcd >> 1) << 3) + bm_l;
      bn = (xcd & 1) * 4 + bn_l;
      z = 0;
    }
  }
  const int layer = layer_base + z;
  const __bf16* Wl = Wq + (size_t)layer * 1024 * KEXT;
  const int wm = wv >> 1, wn = wv & 1;
  const int fr = lane & 15, fq4 = lane >> 4;

  const int tr = t >> 3;                      // row within 32-row group
  const int scol = ((t & 7) ^ (tr & 7)) * 8;  // swizzled element offset

  f32x4 acc[4][4];
#pragma unroll
  for (int mi = 0; mi < 4; ++mi)
#pragma unroll
    for (int ni = 0; ni < 4; ++ni) { f32x4 zz = {0.f, 0.f, 0.f, 0.f}; acc[mi][ni] = zz; }

#define STAGE(kt, buf)                                                         \
  {                                                                            \
    _Pragma("unroll") for (int i = 0; i < 4; ++i) {                            \
      int row = i * 32 + tr;                                                   \
      gld16(A + (size_t)(bm * 128 + row) * KEXT + (kt)*64 + scol,              \
            (char*)lA[buf] + (i * 256 + wv * 64) * 16);                        \
      gld16(Wl + (size_t)(bn * 128 + row) * KEXT + (kt)*64 + scol,             \
            (char*)lB[buf] + (i * 256 + wv * 64) * 16);                        \
    }                                                                          \
  }
#define KCOMPUTE(CUR)                                                          \
  {                                                                            \
    _Pragma("unroll") for (int kk = 0; kk < 2; ++kk) {                         \
      bf16x8 af[4], bfr[4];                                                    \
      _Pragma("unroll") for (int mi = 0; mi < 4; ++mi)                         \
        af[mi] = *(const bf16x8*)&lA[CUR][(wm * 64 + mi * 16 + fr) * 64 +      \
                                          (((kk << 2) | fq4) ^ (fr & 7)) * 8]; \
      _Pragma("unroll") for (int ni = 0; ni < 4; ++ni)                         \
        bfr[ni] = *(const bf16x8*)&lB[CUR][(wn * 64 + ni * 16 + fr) * 64 +     \
                                           (((kk << 2) | fq4) ^ (fr & 7)) * 8];\
      _Pragma("unroll") for (int mi = 0; mi < 4; ++mi)                         \
        _Pragma("unroll") for (int ni = 0; ni < 4; ++ni)                       \
            acc[mi][ni] = MFMA(af[mi], bfr[ni], acc[mi][ni]);                  \
    }                                                                          \
  }

  STAGE(0, 0);
  int cur = 0;
  // Counted-vmcnt 2-barrier schedule: tile kt+1's 8 loads stay in flight
  // across both barriers and land under tile kt's MFMAs (T4).
  for (int kt = 0; kt < 16; ++kt) {
    STAGE(kt + 1, cur ^ 1);
    asm volatile("s_waitcnt vmcnt(8)" ::: "memory");   // tile kt's loads done
    __builtin_amdgcn_s_barrier();                      // all waves' kt loads done
    __builtin_amdgcn_sched_barrier(0);
    __builtin_amdgcn_s_setprio(1);
    KCOMPUTE(cur);
    __builtin_amdgcn_s_setprio(0);
    __builtin_amdgcn_sched_barrier(0);
    __builtin_amdgcn_s_barrier();                      // buf[cur] free to overwrite
    cur ^= 1;
  }
  // tail: tile 16 (no prefetch outstanding beyond it)
  asm volatile("s_waitcnt vmcnt(0)" ::: "memory");
  __builtin_amdgcn_s_barrier();
  __builtin_amdgcn_sched_barrier(0);
  KCOMPUTE(cur);
  __syncthreads();   // full drain before epilogue LDS reuse
#undef STAGE
#undef KCOMPUTE

  // q scale folds 0.1 (dequant), 1/sqrt(64), log2(e) for log2-domain softmax
  const float outmul =
      (mode == 0 && z == 0) ? 0.1f * 0.125f * 1.4426950408889634f : 0.1f;

  if (mode == 0 && z == 2) {
    // --- V^T epilogue: repack via LDS (dead after final barrier) ------------
    __bf16* lw = ((__bf16*)lA) + wv * 4096;   // 8KB wave-private
#pragma unroll
    for (int mi = 0; mi < 4; ++mi) {
      int cc = mi * 2 + (fq4 >> 1), qq = fq4 & 1;
      int sb = (((cc & 4) | (qq << 1) | (cc & 1)) << 3) | ((cc & 2) << 1);
      int lc = sb >> 3, half = (sb >> 2) & 1;
#pragma unroll
      for (int ni = 0; ni < 4; ++ni) {
        int d = ni * 16 + fr;
        __bf16 pk[4];
#pragma unroll
        for (int j = 0; j < 4; ++j) pk[j] = (__bf16)(acc[mi][ni][j] * outmul);
        *(uint2*)&lw[d * 64 + ((lc ^ (d & 7)) << 3) + half * 4] = *(uint2*)pk;
      }
    }
    // same-wave DS ordering: writes visible to own reads, no barrier
    int d = lane;
    int m0 = bm * 128 + wm * 64;
    int b = m0 >> 11, n0 = m0 & 2047;
    int h = bn * 2 + wn;
    __bf16* vrow = vout + ((size_t)(b * 16 + h) * 64 + d) * 2048 + n0;
#pragma unroll
    for (int lc2 = 0; lc2 < 8; ++lc2) {
      uint4 val = *(uint4*)&lw[d * 64 + ((lc2 ^ (d & 7)) << 3)];
      *(uint4*)(vrow + lc2 * 8) = val;
    }
  } else {
#pragma unroll
    for (int mi = 0; mi < 4; ++mi)
#pragma unroll
      for (int ni = 0; ni < 4; ++ni) {
        int o = bn * 128 + wn * 64 + ni * 16 + fr;
#pragma unroll
        for (int j = 0; j < 4; ++j) {
          int m = bm * 128 + wm * 64 + mi * 16 + fq4 * 4 + j;
          float v = acc[mi][ni][j] * outmul;
          if (mode == 0) {
            int b = m >> 11, nr = m & 2047;
            int h = o >> 6, d = o & 63;
            if (z == 0)
              qout[((size_t)(b * 16 + h) * 2048 + nr) * 64 + d] = (__bf16)v;
            else
              kout[((size_t)(b * 16 + h) * 2048 + nr) * 64 + d] = (__bf16)v;
          } else {
            fout[(size_t)m * 1024 + o] = v;
          }
        }
      }
  }
}

// ---------------- flash attention (round 8 pipeline + counted vmcnt) --------
__global__ __launch_bounds__(256) void k_attn(
    const __bf16* __restrict__ qb,   // [bh][n][64] (pre-scaled, log2 domain)
    const __bf16* __restrict__ kb,   // [bh][n][64]
    const __bf16* __restrict__ vbt,  // [bh][64][n] (sigma-permuted n)
    __bf16* __restrict__ attnb) {    // [4096][1088] (ext cols = head means)
  __shared__ __align__(16) __bf16 lK[2][64 * 64];
  __shared__ __align__(16) __bf16 lVT[2][64 * 64];

  const int t = threadIdx.x, lane = t & 63, wv = t >> 6;
  // T1: XCD rect = 4bh x 16qt -> each bh's K/V fetched by one XCD only
  const int xcd = blockIdx.x & 7, local = blockIdx.x >> 3;   // local 0..63
  const int bh = xcd * 4 + (local >> 4);
  const int qt = local & 15;                   // 0..15 (128 q-rows per block)
  const int fr = lane & 15, g = lane >> 4;
  const int qrow0 = qt * 128 + wv * 16;
  const size_t hbase = (size_t)bh * 2048 * 64;

  const int srow0 = t >> 3, sc0 = (t & 7) ^ (srow0 & 7);
  const int srow1 = (256 + t) >> 3, sc1 = (t & 7) ^ (srow1 & 7);
  const int dst0 = (wv * 64) * 16, dst1 = (256 + wv * 64) * 16;

  bf16x8 qf[2][2];
#pragma unroll
  for (int s = 0; s < 2; ++s)
#pragma unroll
    for (int kk = 0; kk < 2; ++kk)
      qf[s][kk] = *(const bf16x8*)(qb + hbase + (size_t)(qrow0 + s * 64 + fr) * 64 +
                                   kk * 32 + g * 8);

  bf16x8 vones;
#pragma unroll
  for (int e = 0; e < 8; ++e) vones[e] = (__bf16)1.0f;

  f32x4 o[2][4], o4[2];
#pragma unroll
  for (int s = 0; s < 2; ++s) {
#pragma unroll
    for (int di = 0; di < 4; ++di) { f32x4 zz = {0.f, 0.f, 0.f, 0.f}; o[s][di] = zz; }
    f32x4 zz = {0.f, 0.f, 0.f, 0.f};
    o4[s] = zz;
  }

  f32x4 smA[2][4], smB[2][4];

#define SK_STAGE(KT, BUF)                                                      \
  {                                                                            \
    int kn = (KT)*64;                                                          \
    gld16(kb + hbase + (size_t)(kn + srow0) * 64 + sc0 * 8, (char*)(BUF) + dst0); \
    gld16(kb + hbase + (size_t)(kn + srow1) * 64 + sc1 * 8, (char*)(BUF) + dst1); \
  }
#define SV_STAGE(KT, BUF)                                                      \
  {                                                                            \
    int kn = (KT)*64;                                                          \
    gld16(vbt + hbase + (size_t)srow0 * 2048 + kn + sc0 * 8, (char*)(BUF) + dst0); \
    gld16(vbt + hbase + (size_t)srow1 * 2048 + kn + sc1 * 8, (char*)(BUF) + dst1); \
  }
#define QK_STEP(KBUF, SM)                                                      \
  {                                                                            \
    _Pragma("unroll") for (int ni = 0; ni < 4; ++ni) {                         \
      f32x4 zz = {0.f, 0.f, 0.f, 0.f};                                         \
      SM[0][ni] = zz;                                                          \
      SM[1][ni] = zz;                                                          \
    }                                                                          \
    _Pragma("unroll") for (int kk = 0; kk < 2; ++kk)                           \
        _Pragma("unroll") for (int ni = 0; ni < 4; ++ni) {                     \
      bf16x8 kf = *(const bf16x8*)&(KBUF)[(ni * 16 + fr) * 64 +                \
                                          (((kk << 2) | g) ^ (fr & 7)) * 8];   \
      SM[0][ni] = MFMA(kf, qf[0][kk], SM[0][ni]);                              \
      SM[1][ni] = MFMA(kf, qf[1][kk], SM[1][ni]);                              \
    }                                                                          \
  }
#define EXPPV_STEP(SM, VBUF)                                                   \
  {                                                                            \
    bf16x8 pa[2][2];                                                           \
    _Pragma("unroll") for (int s2 = 0; s2 < 2; ++s2)                           \
        _Pragma("unroll") for (int kk = 0; kk < 2; ++kk)                       \
            _Pragma("unroll") for (int e = 0; e < 8; ++e)                      \
                pa[s2][kk][e] = (__bf16)__builtin_amdgcn_exp2f(                \
                    SM[s2][2 * kk + (e >> 2)][e & 3]);                         \
    _Pragma("unroll") for (int kk = 0; kk < 2; ++kk) {                         \
      const int ncr = ((kk << 2) | ((g & 1) << 1) | (g >> 1)) ^ (fr & 7);      \
      _Pragma("unroll") for (int di = 0; di < 4; ++di) {                       \
        bf16x8 vf = *(const bf16x8*)&(VBUF)[(di * 16 + fr) * 64 + ncr * 8];    \
        o[0][di] = MFMA(pa[0][kk], vf, o[0][di]);                              \
        o[1][di] = MFMA(pa[1][kk], vf, o[1][di]);                              \
      }                                                                        \
      o4[0] = MFMA(pa[0][kk], vones, o4[0]);                                   \
      o4[1] = MFMA(pa[1][kk], vones, o4[1]);                                   \
    }                                                                          \
  }
// counted-vmcnt half: issue loads, wait prev half's loads, barrier, compute,
// barrier (buffer-read-done). Loads issued here stay in flight across both.
#define WAITBAR(N)                                                             \
  asm volatile("s_waitcnt vmcnt(" #N ")" ::: "memory");                        \
  __builtin_amdgcn_s_barrier();                                                \
  __builtin_amdgcn_sched_barrier(0);
#define ENDBAR                                                                 \
  __builtin_amdgcn_sched_barrier(0);                                           \
  __builtin_amdgcn_s_barrier();

  // prologue: K(0) staged (2 loads in flight)
  SK_STAGE(0, lK[0]);

  for (int it = 0; it < 15; ++it) {
    int t2 = it * 2;
    // ---- even half: tile t2 ----
    SK_STAGE(t2 + 1, lK[1]);
    SV_STAGE(t2, lVT[0]);
    WAITBAR(4)                       // prev-odd's 4 (K(t2),V(t2-1)) done
    __builtin_amdgcn_s_setprio(1);
    QK_STEP(lK[0], smB);
    if (it > 0) { EXPPV_STEP(smA, lVT[1]); }
    __builtin_amdgcn_s_setprio(0);
    ENDBAR
    // ---- odd half: tile t2+1 ----
    SK_STAGE(t2 + 2, lK[0]);
    SV_STAGE(t2 + 1, lVT[1]);
    WAITBAR(4)                       // even's 4 (K(t2+1),V(t2)) done
    __builtin_amdgcn_s_setprio(1);
    QK_STEP(lK[1], smA);
    EXPPV_STEP(smB, lVT[0]);
    __builtin_amdgcn_s_setprio(0);
    ENDBAR
  }
  // ---- peeled it=15: tiles 30, 31 ----
  SK_STAGE(31, lK[1]);
  SV_STAGE(30, lVT[0]);
  WAITBAR(4)
  __builtin_amdgcn_s_setprio(1);
  QK_STEP(lK[0], smB);
  EXPPV_STEP(smA, lVT[1]);           // S(29), V(29)
  __builtin_amdgcn_s_setprio(0);
  ENDBAR
  SV_STAGE(31, lVT[1]);
  WAITBAR(2)                         // even's 4 done (2 newer = V(31))
  __builtin_amdgcn_s_setprio(1);
  QK_STEP(lK[1], smA);
  EXPPV_STEP(smB, lVT[0]);           // S(30), V(30)
  __builtin_amdgcn_s_setprio(0);
  ENDBAR
  WAITBAR(0)                         // V(31) done
  EXPPV_STEP(smA, lVT[1]);           // S(31), V(31)

#undef SK_STAGE
#undef SV_STAGE
#undef QK_STEP
#undef EXPPV_STEP
#undef WAITBAR
#undef ENDBAR

  // epilogue: normalize, write attn bf16 into stride-1088 rows + ext cols
  const int b = bh >> 4, h = bh & 15;
#pragma unroll
  for (int s = 0; s < 2; ++s)
#pragma unroll
    for (int j = 0; j < 4; ++j) {
      float inv = 1.f / o4[s][j];
      int nr = qt * 128 + s * 64 + wv * 16 + g * 4 + j;
      size_t rowbase = (size_t)(b * 2048 + nr) * KEXT;
      float rowsum = 0.f;
#pragma unroll
      for (int di = 0; di < 4; ++di) {
        float vv = o[s][di][j] * inv;
        attnb[rowbase + h * 64 + di * 16 + fr] = (__bf16)vv;
        rowsum += vv;
      }
      rowsum = redsum16(rowsum);
      if (fr == 0) attnb[rowbase + 1024 + h] = (__bf16)(rowsum * (1.f / 64.f));
      if (h < 3) attnb[rowbase + 1040 + h * 16 + fr] = (__bf16)0.f;  // zero pad
    }
}

// ---------------- launch ----------------
extern "C" void kernel_launch(void* const* d_in, const int* in_sizes, int n_in,
                              void* d_out, int out_size, void* d_ws, size_t ws_size,
                              hipStream_t stream) {
  const float* x = (const float*)d_in[0];
  const float* w_[4]  = {(const float*)d_in[1], (const float*)d_in[4],
                         (const float*)d_in[7], (const float*)d_in[10]};
  const float* dW_[4] = {(const float*)d_in[2], (const float*)d_in[5],
                         (const float*)d_in[8], (const float*)d_in[11]};
  const float* dB_[4] = {(const float*)d_in[3], (const float*)d_in[6],
                         (const float*)d_in[9], (const float*)d_in[12]};
  float* out = (float*)d_out;

  char* ws = (char*)d_ws;
  const size_t MB = 1ull << 20;
  __bf16* xbf   = (__bf16*)(ws);                 // 4096*1088*2 = 8.9 MB
  __bf16* attnb = xbf;                           // alias: xbf dead after QKV GEMM
  __bf16* wq    = (__bf16*)(ws + 9 * MB);        // 4*1024*1088*2 = 8.9 MB
  __bf16* qb    = (__bf16*)(ws + 18 * MB);       // 8 MB
  __bf16* kb    = (__bf16*)(ws + 26 * MB);       // 8 MB
  __bf16* vbt   = (__bf16*)(ws + 34 * MB);       // 8 MB -> ends 42 MB

  k_quant_w<<<4096, 256, 0, stream>>>(w_[0], w_[1], w_[2], w_[3], wq);
  k_xprep<<<4096, 256, 0, stream>>>(x, xbf);
  k_delta<<<256, 256, 0, stream>>>(dW_[0], dB_[0], dW_[1], dB_[1],
                                   dW_[2], dB_[2], dW_[3], dB_[3], wq);
  k_gemm<<<768, 256, 0, stream>>>(xbf, wq, qb, kb, vbt, nullptr, 0, 0);
  k_attn<<<512, 256, 0, stream>>>(qb, kb, vbt, attnb);
  k_gemm<<<256, 256, 0, stream>>>(attnb, wq, nullptr, nullptr, nullptr,
                                  out, 1, 3);
}